// Round 10
// baseline (112.256 us; speedup 1.0000x reference)
//
#include <hip/hip_runtime.h>
#include <math.h>
#include <type_traits>

#define CTHREADS 128   // conv kernels
#define THREADS 256    // aux kernels
constexpr int BATCH = 16;

// ---------------------------------------------------------------------------
// Radial-class conv (rounds 6-9) + round 10: per-block weight/basis synthesis
// (synth kernel removed; normalization via analytic class multiplicities) and
// tier A+ (conv1 G=10) for 2x wave count when workspace allows.
//
// Workspace (floats):
//   XM 320
//   A0 [16][20][33][33][36] : 12,545,280   (rows padded 33->36)
//   A1 [16][20][18][18][20] :  2,073,600   (rows padded 18->20)
//   P1 [G1][16][23][5832]   (A+ G1=10: 21,461,760 -> 144.3 MB total)
//   P2 [20][16][20][1000] aliases A0 (6.4M < 12.5M).
// ---------------------------------------------------------------------------

__host__ __device__ constexpr int QI(int q) {  // q = ay^2+ax^2 in {0,1,2,4,5,8}
  return q == 0 ? 0 : q == 1 ? 1 : q == 2 ? 2 : q == 4 ? 3 : q == 5 ? 4 : 5;
}

// Direct conv via radial classes. Thread = 2 x-consecutive voxels, ALL OC
// channels of one ic-group. Block index XCD-pinned: bid&7 = xcd, b = xcd+8*bh.
// Per-block prologue synthesizes the 10-class basis values BV (exp + analytic
// normalization: sum_taps B^2 = sum_g mult_g bv_g^2) and the weight slice lw
// straight from W. Plane loads lambda-local (bounded liveness, rounds 3-5/8
// lessons). EPI: 0 = partials [g][b][OC][vox] packed, 1 = gated 20ch, 2 = plain.
template <int ICTOT, int ICG, int OC, int OCP, int DIN, int DOUT, int IRS, int ORS,
          int C4N, int EPI>
__global__ __launch_bounds__(CTHREADS)
void conv_kernel(const float* __restrict__ in, const float* __restrict__ W,
                 float* __restrict__ out) {
  constexpr int G = ICTOT / ICG;
  constexpr int ISLAB = DIN * DIN * IRS;
  constexpr int OSLAB = DOUT * DOUT * ORS;
  constexpr int XS = (DOUT + 1) / 2;
  constexpr int SPI = DOUT * DOUT * XS;
  constexpr int NB = (SPI + CTHREADS - 1) / CTHREADS;
  constexpr int CW = C4N * 4;
  static_assert(CW == OCP, "full-width acc");

  __shared__ __align__(16) float lbv[40];
  __shared__ float lnrm[4];
  __shared__ __align__(16) float lw[ICG * 3 * CW];

  // XCD-pinned decode (grid = 8 * NB * G * (BATCH/8))
  const int bid = blockIdx.x;
  const int xcd = bid & 7;
  int slot = bid >> 3;
  const int chunk = slot % NB;
  slot /= NB;
  const int g = slot % G;
  const int bh = slot / G;
  const int b = xcd + 8 * bh;
  const int t = threadIdx.x;

  // ---- per-block basis synthesis (replaces synth kernel) ----
  if (t < 40) {
    const int gc = t >> 2, j = t & 3;
    const float R2C[10] = {0.f, 1.f, 2.f, 3.f, 4.f, 5.f, 6.f, 8.f, 9.f, 12.f};
    float raw = 0.f;
    if (j < 3) {
      const float d = (sqrtf(R2C[gc]) - (float)j) * (1.0f / 0.6f);
      raw = expf(-0.5f * d * d);
    }
    lbv[t] = raw;
  }
  __syncthreads();
  if (t < 3) {
    const float MULT[10] = {1.f, 6.f, 12.f, 8.f, 6.f, 24.f, 24.f, 12.f, 24.f, 8.f};
    float ssum = 0.f;
    for (int gc = 0; gc < 10; ++gc) {
      const float v = lbv[gc * 4 + t];
      ssum += MULT[gc] * v * v;
    }
    lnrm[t] = rsqrtf(ssum);
  }
  __syncthreads();
  if (t < 40) lbv[t] = ((t & 3) < 3) ? lbv[t] * lnrm[t & 3] : 0.f;
  for (int i = t; i < ICG * 3 * CW; i += CTHREADS) {
    const int cc = i % CW;
    const int jj = (i / CW) % 3;
    const int icl = i / (3 * CW);
    const int ic = g * ICG + icl;
    lw[i] = (cc < OC) ? W[((size_t)cc * ICTOT + ic) * 3 + jj] : 0.f;
  }
  __syncthreads();

  const int s = chunk * CTHREADS + t;
  const bool active = s < SPI;
  const int si = active ? s : 0;
  const int zo = si / (DOUT * XS);
  const int yo = (si / XS) % DOUT;
  const int xo0 = (si % XS) * 2;

  float acc[CW][2];
#pragma unroll
  for (int c = 0; c < CW; ++c) {
    acc[c][0] = 0.f;
    acc[c][1] = 0.f;
  }

  const float* __restrict__ ip0 = in + (size_t)(b * ICTOT + g * ICG) * ISLAB;
  const int offA = max(2 * xo0 - 4, 0);
  const int offB = min(2 * xo0, IRS - 4);
  bool xok[7];
#pragma unroll
  for (int p = 0; p < 7; ++p) xok[p] = (unsigned)(2 * xo0 - 3 + p) < (unsigned)DIN;
  int yoff[5];
  bool yok[5];
#pragma unroll
  for (int ky = 0; ky < 5; ++ky) {
    const int yi = 2 * yo - 3 + ky;
    yok[ky] = (unsigned)yi < (unsigned)DIN;
    yoff[ky] = min(max(yi, 0), DIN - 1) * IRS;
  }

#pragma unroll 1
  for (int icl = 0; icl < ICG; ++icl) {
    const float* __restrict__ ipc = ip0 + (size_t)icl * ISLAB;
    float sg[10][2];
#pragma unroll
    for (int gg = 0; gg < 10; ++gg) {
      sg[gg][0] = 0.f;
      sg[gg][1] = 0.f;
    }

    auto plane = [&](auto azc_c, int kz) {
      constexpr int AZC = decltype(azc_c)::value;
      constexpr int GM[3][6] = {
          {0, 1, 2, 4, 5, 7}, {1, 2, 3, 5, 6, 8}, {4, 5, 6, 7, 8, 9}};
      constexpr int A2[5] = {4, 1, 0, 1, 4};
      const int zi = 2 * zo - 3 + kz;
      const bool zok = (unsigned)zi < (unsigned)DIN;
      const float* pl = ipc + (size_t)min(max(zi, 0), DIN - 1) * (DIN * IRS);
      float4 pa[5], pb[5];
#pragma unroll
      for (int ky = 0; ky < 5; ++ky) {
        const float* row = pl + yoff[ky];
        pa[ky] = *(const float4*)(row + offA);
        pb[ky] = *(const float4*)(row + offB);
      }
      float pq[6][2];
#pragma unroll
      for (int qi = 0; qi < 6; ++qi) {
        pq[qi][0] = 0.f;
        pq[qi][1] = 0.f;
      }
#pragma unroll
      for (int ky = 0; ky < 5; ++ky) {
        float v[7] = {pa[ky].y, pa[ky].z, pa[ky].w, pb[ky].x, pb[ky].y, pb[ky].z, pb[ky].w};
        const bool yz = zok && yok[ky];
#pragma unroll
        for (int p = 0; p < 7; ++p) v[p] = (yz && xok[p]) ? v[p] : 0.f;
#pragma unroll
        for (int kx = 0; kx < 5; ++kx) {
          pq[QI(A2[ky] + A2[kx])][0] += v[kx];
          pq[QI(A2[ky] + A2[kx])][1] += v[2 + kx];
        }
      }
#pragma unroll
      for (int qi = 0; qi < 6; ++qi) {
        sg[GM[AZC][qi]][0] += pq[qi][0];
        sg[GM[AZC][qi]][1] += pq[qi][1];
      }
    };

    plane(std::integral_constant<int, 0>{}, 2);
#pragma unroll 1
    for (int rep = 0; rep < 2; ++rep) plane(std::integral_constant<int, 1>{}, 1 + 2 * rep);
#pragma unroll 1
    for (int rep = 0; rep < 2; ++rep) plane(std::integral_constant<int, 2>{}, 4 * rep);

    float z[3][2];
#pragma unroll
    for (int j = 0; j < 3; ++j) {
      z[j][0] = 0.f;
      z[j][1] = 0.f;
    }
#pragma unroll
    for (int gg = 0; gg < 10; ++gg) {
      const float4 bv4 = *(const float4*)&lbv[gg * 4];
#pragma unroll
      for (int n = 0; n < 2; ++n) {
        z[0][n] = fmaf(bv4.x, sg[gg][n], z[0][n]);
        z[1][n] = fmaf(bv4.y, sg[gg][n], z[1][n]);
        z[2][n] = fmaf(bv4.z, sg[gg][n], z[2][n]);
      }
    }
#pragma unroll
    for (int j = 0; j < 3; ++j) {
#pragma unroll
      for (int c4 = 0; c4 < C4N; ++c4) {
        const float4 w4 = *(const float4*)&lw[(icl * 3 + j) * CW + 4 * c4];
#pragma unroll
        for (int n = 0; n < 2; ++n) {
          acc[c4 * 4 + 0][n] = fmaf(w4.x, z[j][n], acc[c4 * 4 + 0][n]);
          acc[c4 * 4 + 1][n] = fmaf(w4.y, z[j][n], acc[c4 * 4 + 1][n]);
          acc[c4 * 4 + 2][n] = fmaf(w4.z, z[j][n], acc[c4 * 4 + 2][n]);
          acc[c4 * 4 + 3][n] = fmaf(w4.w, z[j][n], acc[c4 * 4 + 3][n]);
        }
      }
    }
  }

  if (!active) return;
  const int vbase = (zo * DOUT + yo) * ORS + xo0;

  if constexpr (EPI == 1) {
    float* __restrict__ op = out + (size_t)b * 20 * OSLAB + vbase;
#pragma unroll
    for (int n = 0; n < 2; ++n) {
      if (xo0 + n < DOUT) {
        const float g0 = 1.f / (1.f + expf(-acc[20][n]));
        const float g1 = 1.f / (1.f + expf(-acc[21][n]));
        const float g2 = 1.f / (1.f + expf(-acc[22][n]));
#pragma unroll
        for (int c = 0; c < 5; ++c) op[(size_t)c * OSLAB + n] = fmaxf(acc[c][n], 0.f);
#pragma unroll
        for (int c = 0; c < 3; ++c) op[(size_t)(5 + c) * OSLAB + n] = acc[5 + c][n] * g0;
#pragma unroll
        for (int c = 0; c < 5; ++c) op[(size_t)(8 + c) * OSLAB + n] = acc[8 + c][n] * g1;
#pragma unroll
        for (int c = 0; c < 7; ++c) op[(size_t)(13 + c) * OSLAB + n] = acc[13 + c][n] * g2;
      }
    }
  } else if constexpr (EPI == 0) {
    float* __restrict__ op = out + ((size_t)(g * BATCH + b) * OC) * OSLAB + vbase;
#pragma unroll
    for (int c = 0; c < CW; ++c) {
      if (c < OC) {
#pragma unroll
        for (int n = 0; n < 2; ++n)
          if (xo0 + n < DOUT) op[(size_t)c * OSLAB + n] = acc[c][n];
      }
    }
  } else {
    float* __restrict__ op = out + (size_t)b * OC * OSLAB + vbase;
#pragma unroll
    for (int c = 0; c < CW; ++c) {
      if (c < OC) {
#pragma unroll
        for (int n = 0; n < 2; ++n)
          if (xo0 + n < DOUT) op[(size_t)c * OSLAB + n] = acc[c][n];
      }
    }
  }
}

// Sum ic-group partials (23 ch, packed) + gating -> A1 padded (row stride 20).
template <int G>
__global__ __launch_bounds__(THREADS)
void combine_gate_kernel(const float* __restrict__ P, float* __restrict__ out) {
  const int tid = blockIdx.x * THREADS + threadIdx.x;
  if (tid >= BATCH * 5832) return;
  const int vox = tid % 5832;
  const int b = tid / 5832;
  float s[23];
#pragma unroll
  for (int oc = 0; oc < 23; ++oc) s[oc] = 0.f;
  for (int g = 0; g < G; ++g) {
    const float* __restrict__ p = P + ((size_t)(g * BATCH + b) * 23) * 5832 + vox;
#pragma unroll
    for (int oc = 0; oc < 23; ++oc) s[oc] += p[(size_t)oc * 5832];
  }
  const float g0 = 1.f / (1.f + expf(-s[20]));
  const float g1 = 1.f / (1.f + expf(-s[21]));
  const float g2 = 1.f / (1.f + expf(-s[22]));
  const int zz = vox / 324, yy = (vox / 18) % 18, xx = vox % 18;
  float* __restrict__ op = out + (size_t)b * 20 * 6480 + (zz * 18 + yy) * 20 + xx;
#pragma unroll
  for (int c = 0; c < 5; ++c) op[(size_t)c * 6480] = fmaxf(s[c], 0.f);
#pragma unroll
  for (int c = 0; c < 3; ++c) op[(size_t)(5 + c) * 6480] = s[5 + c] * g0;
#pragma unroll
  for (int c = 0; c < 5; ++c) op[(size_t)(8 + c) * 6480] = s[8 + c] * g1;
#pragma unroll
  for (int c = 0; c < 7; ++c) op[(size_t)(13 + c) * 6480] = s[13 + c] * g2;
}

// AvgSpacial stage 1: one block per (b,ch), float4 loads, -> XM[b*20+ch].
template <int G>
__global__ __launch_bounds__(THREADS)
void reduce_kernel(const float* __restrict__ P2, float* __restrict__ XM) {
  const int b = blockIdx.x / 20, ch = blockIdx.x % 20;
  const int t = threadIdx.x;
  float s = 0.f;
  for (int i = t; i < G * 250; i += THREADS) {
    const int g = i / 250, v = i % 250;
    const float4 x = *(const float4*)(P2 + ((size_t)(g * BATCH + b) * 20 + ch) * 1000 + v * 4);
    s += x.x + x.y + x.z + x.w;
  }
  __shared__ float red[THREADS];
  red[t] = s;
  __syncthreads();
  for (int st = THREADS / 2; st > 0; st >>= 1) {
    if (t < st) red[t] += red[t + st];
    __syncthreads();
  }
  if (t == 0) XM[b * 20 + ch] = red[0] * (1.0f / 1000.0f);
}

// AvgSpacial stage 2: fc1(relu) + fc2 for all batches, one block.
__global__ __launch_bounds__(THREADS)
void fc_kernel(const float* __restrict__ XM,
               const float* __restrict__ fc1w, const float* __restrict__ fc1b,
               const float* __restrict__ fc2w, const float* __restrict__ fc2b,
               float* __restrict__ out) {
  const int t = threadIdx.x;
  __shared__ float xs[320];
  __shared__ float hh[800];
  for (int i = t; i < 320; i += THREADS) xs[i] = XM[i];
  __syncthreads();
  for (int i = t; i < 800; i += THREADS) {
    const int b = i / 50, j = i % 50;
    float s = fc1b[j];
    for (int c = 0; c < 20; ++c) s += xs[b * 20 + c] * fc1w[j * 20 + c];
    hh[i] = fmaxf(s, 0.f);
  }
  __syncthreads();
  for (int i = t; i < 32; i += THREADS) {
    const int b = i / 2, k = i % 2;
    float s = fc2b[k];
    for (int j = 0; j < 50; ++j) s += hh[b * 50 + j] * fc2w[k * 50 + j];
    out[b * 2 + k] = s;
  }
}

extern "C" void kernel_launch(void* const* d_in, const int* in_sizes, int n_in,
                              void* d_out, int out_size, void* d_ws, size_t ws_size,
                              hipStream_t stream) {
  (void)in_sizes; (void)n_in; (void)out_size;
  const float* inp  = (const float*)d_in[0];
  const float* W0   = (const float*)d_in[1];
  const float* W1   = (const float*)d_in[2];
  const float* W2   = (const float*)d_in[3];
  const float* fc1w = (const float*)d_in[4];
  const float* fc1b = (const float*)d_in[5];
  const float* fc2w = (const float*)d_in[6];
  const float* fc2b = (const float*)d_in[7];
  float* out = (float*)d_out;

  float* ws = (float*)d_ws;
  float* XM  = ws;                       // 320
  float* A0  = XM + 320;                 // 12,545,280 (padded rows 36)
  float* A1  = A0 + (size_t)12545280;    // 2,073,600  (padded rows 20)
  float* P1  = A1 + (size_t)2073600;     // variable
  float* P2  = A0;                       // conv2 partials alias dead A0

  const size_t favail = ws_size / 4;
  const size_t fixed = 320 + (size_t)12545280 + 2073600;  // 14,619,200

  // conv0: SPI=18513, NB=145, grid 8*145*1*2 = 2320.
  hipLaunchKernelGGL((conv_kernel<1, 1, 23, 24, 64, 33, 64, 36, 6, 1>), dim3(2320),
                     dim3(CTHREADS), 0, stream, inp, W0, A0);

  if (favail >= fixed + (size_t)10 * BATCH * 23 * 5832) {
    // Tier A+: conv1 G=10 (ICG=2), NB=23 -> grid 8*23*10*2 = 3680 (7360 waves).
    hipLaunchKernelGGL((conv_kernel<20, 2, 23, 24, 33, 18, 36, 18, 6, 0>), dim3(3680),
                       dim3(CTHREADS), 0, stream, A0, W1, P1);
    hipLaunchKernelGGL((combine_gate_kernel<10>), dim3((16 * 5832 + THREADS - 1) / THREADS),
                       dim3(THREADS), 0, stream, P1, A1);
    hipLaunchKernelGGL((conv_kernel<20, 1, 20, 20, 18, 10, 20, 10, 5, 0>), dim3(1280),
                       dim3(CTHREADS), 0, stream, A1, W2, P2);
    hipLaunchKernelGGL(reduce_kernel<20>, dim3(320), dim3(THREADS), 0, stream, P2, XM);
    hipLaunchKernelGGL(fc_kernel, dim3(1), dim3(THREADS), 0, stream, XM, fc1w, fc1b, fc2w, fc2b,
                       out);
  } else if (favail >= fixed + (size_t)5 * BATCH * 23 * 5832) {
    // Tier A: conv1 G=5 (ICG=4) -> grid 1840.
    hipLaunchKernelGGL((conv_kernel<20, 4, 23, 24, 33, 18, 36, 18, 6, 0>), dim3(1840),
                       dim3(CTHREADS), 0, stream, A0, W1, P1);
    hipLaunchKernelGGL((combine_gate_kernel<5>), dim3((16 * 5832 + THREADS - 1) / THREADS),
                       dim3(THREADS), 0, stream, P1, A1);
    hipLaunchKernelGGL((conv_kernel<20, 1, 20, 20, 18, 10, 20, 10, 5, 0>), dim3(1280),
                       dim3(CTHREADS), 0, stream, A1, W2, P2);
    hipLaunchKernelGGL(reduce_kernel<20>, dim3(320), dim3(THREADS), 0, stream, P2, XM);
    hipLaunchKernelGGL(fc_kernel, dim3(1), dim3(THREADS), 0, stream, XM, fc1w, fc1b, fc2w, fc2b,
                       out);
  } else if (favail >= fixed + (size_t)2 * BATCH * 23 * 5832) {
    // Tier C: conv1 G=2 (ICG=10) -> grid 736.
    hipLaunchKernelGGL((conv_kernel<20, 10, 23, 24, 33, 18, 36, 18, 6, 0>), dim3(736),
                       dim3(CTHREADS), 0, stream, A0, W1, P1);
    hipLaunchKernelGGL((combine_gate_kernel<2>), dim3((16 * 5832 + THREADS - 1) / THREADS),
                       dim3(THREADS), 0, stream, P1, A1);
    hipLaunchKernelGGL((conv_kernel<20, 1, 20, 20, 18, 10, 20, 10, 5, 0>), dim3(1280),
                       dim3(CTHREADS), 0, stream, A1, W2, P2);
    hipLaunchKernelGGL(reduce_kernel<20>, dim3(320), dim3(THREADS), 0, stream, P2, XM);
    hipLaunchKernelGGL(fc_kernel, dim3(1), dim3(THREADS), 0, stream, XM, fc1w, fc1b, fc2w, fc2b,
                       out);
  } else {
    // Tier D: fused fallback. conv1 gated -> A1 padded, conv2 plain -> A2.
    float* A2 = P1;
    hipLaunchKernelGGL((conv_kernel<20, 20, 23, 24, 33, 18, 36, 20, 6, 1>), dim3(368),
                       dim3(CTHREADS), 0, stream, A0, W1, A1);
    hipLaunchKernelGGL((conv_kernel<20, 20, 20, 20, 18, 10, 20, 10, 5, 2>), dim3(64),
                       dim3(CTHREADS), 0, stream, A1, W2, A2);
    hipLaunchKernelGGL(reduce_kernel<1>, dim3(320), dim3(THREADS), 0, stream, A2, XM);
    hipLaunchKernelGGL(fc_kernel, dim3(1), dim3(THREADS), 0, stream, XM, fc1w, fc1b, fc2w, fc2b,
                       out);
  }
}

// Round 11
// 99.925 us; speedup vs baseline: 1.1234x; 1.1234x over previous
//
#include <hip/hip_runtime.h>
#include <math.h>
#include <type_traits>

#define CTHREADS 128   // conv kernels
#define THREADS 256    // aux kernels
constexpr int BATCH = 16;

// ---------------------------------------------------------------------------
// Radial-class conv (rounds 6-10) + round 11: conv1 back to G=5 (G=10 doubled
// partials traffic and regressed), and conv2 reduced IN-KERNEL: its output is
// only consumed via AvgSpacial, so each block emits one 20-float partial sum
// (P2S, deterministic order) instead of 25.6 MB of voxels; fc sums P2S.
//
// Workspace (floats):
//   A0 [16][20][33][33][36] : 12,545,280   (rows padded 33->36)
//   A1 [16][20][18][18][20] :  2,073,600   (rows padded 18->20)
//   P2S [20][16][20][4]     :     25,600
//   P1 [G1][16][23][5832]   (tier A G1=5: 10,730,880 -> 101.5 MB total)
// ---------------------------------------------------------------------------

__host__ __device__ constexpr int QI(int q) {  // q = ay^2+ax^2 in {0,1,2,4,5,8}
  return q == 0 ? 0 : q == 1 ? 1 : q == 2 ? 2 : q == 4 ? 3 : q == 5 ? 4 : 5;
}

// Direct conv via radial classes. Thread = 2 x-consecutive voxels, ALL OC
// channels of one ic-group. Block index XCD-pinned: bid&7 = xcd, b = xcd+8*bh.
// Per-block prologue synthesizes basis values + weight slice from W.
// EPI: 0 = partials [g][b][OC][vox] packed, 1 = gated 20ch, 2 = plain.
template <int ICTOT, int ICG, int OC, int OCP, int DIN, int DOUT, int IRS, int ORS,
          int C4N, int EPI>
__global__ __launch_bounds__(CTHREADS)
void conv_kernel(const float* __restrict__ in, const float* __restrict__ W,
                 float* __restrict__ out) {
  constexpr int G = ICTOT / ICG;
  constexpr int ISLAB = DIN * DIN * IRS;
  constexpr int OSLAB = DOUT * DOUT * ORS;
  constexpr int XS = (DOUT + 1) / 2;
  constexpr int SPI = DOUT * DOUT * XS;
  constexpr int NB = (SPI + CTHREADS - 1) / CTHREADS;
  constexpr int CW = C4N * 4;
  static_assert(CW == OCP, "full-width acc");

  __shared__ __align__(16) float lbv[40];
  __shared__ float lnrm[4];
  __shared__ __align__(16) float lw[ICG * 3 * CW];

  const int bid = blockIdx.x;
  const int xcd = bid & 7;
  int slot = bid >> 3;
  const int chunk = slot % NB;
  slot /= NB;
  const int g = slot % G;
  const int bh = slot / G;
  const int b = xcd + 8 * bh;
  const int t = threadIdx.x;

  // per-block basis synthesis
  if (t < 40) {
    const int gc = t >> 2, j = t & 3;
    const float R2C[10] = {0.f, 1.f, 2.f, 3.f, 4.f, 5.f, 6.f, 8.f, 9.f, 12.f};
    float raw = 0.f;
    if (j < 3) {
      const float d = (sqrtf(R2C[gc]) - (float)j) * (1.0f / 0.6f);
      raw = expf(-0.5f * d * d);
    }
    lbv[t] = raw;
  }
  __syncthreads();
  if (t < 3) {
    const float MULT[10] = {1.f, 6.f, 12.f, 8.f, 6.f, 24.f, 24.f, 12.f, 24.f, 8.f};
    float ssum = 0.f;
    for (int gc = 0; gc < 10; ++gc) {
      const float v = lbv[gc * 4 + t];
      ssum += MULT[gc] * v * v;
    }
    lnrm[t] = rsqrtf(ssum);
  }
  __syncthreads();
  if (t < 40) lbv[t] = ((t & 3) < 3) ? lbv[t] * lnrm[t & 3] : 0.f;
  for (int i = t; i < ICG * 3 * CW; i += CTHREADS) {
    const int cc = i % CW;
    const int jj = (i / CW) % 3;
    const int icl = i / (3 * CW);
    const int ic = g * ICG + icl;
    lw[i] = (cc < OC) ? W[((size_t)cc * ICTOT + ic) * 3 + jj] : 0.f;
  }
  __syncthreads();

  const int s = chunk * CTHREADS + t;
  const bool active = s < SPI;
  const int si = active ? s : 0;
  const int zo = si / (DOUT * XS);
  const int yo = (si / XS) % DOUT;
  const int xo0 = (si % XS) * 2;

  float acc[CW][2];
#pragma unroll
  for (int c = 0; c < CW; ++c) {
    acc[c][0] = 0.f;
    acc[c][1] = 0.f;
  }

  const float* __restrict__ ip0 = in + (size_t)(b * ICTOT + g * ICG) * ISLAB;
  const int offA = max(2 * xo0 - 4, 0);
  const int offB = min(2 * xo0, IRS - 4);
  bool xok[7];
#pragma unroll
  for (int p = 0; p < 7; ++p) xok[p] = (unsigned)(2 * xo0 - 3 + p) < (unsigned)DIN;
  int yoff[5];
  bool yok[5];
#pragma unroll
  for (int ky = 0; ky < 5; ++ky) {
    const int yi = 2 * yo - 3 + ky;
    yok[ky] = (unsigned)yi < (unsigned)DIN;
    yoff[ky] = min(max(yi, 0), DIN - 1) * IRS;
  }

#pragma unroll 1
  for (int icl = 0; icl < ICG; ++icl) {
    const float* __restrict__ ipc = ip0 + (size_t)icl * ISLAB;
    float sg[10][2];
#pragma unroll
    for (int gg = 0; gg < 10; ++gg) {
      sg[gg][0] = 0.f;
      sg[gg][1] = 0.f;
    }

    auto plane = [&](auto azc_c, int kz) {
      constexpr int AZC = decltype(azc_c)::value;
      constexpr int GM[3][6] = {
          {0, 1, 2, 4, 5, 7}, {1, 2, 3, 5, 6, 8}, {4, 5, 6, 7, 8, 9}};
      constexpr int A2[5] = {4, 1, 0, 1, 4};
      const int zi = 2 * zo - 3 + kz;
      const bool zok = (unsigned)zi < (unsigned)DIN;
      const float* pl = ipc + (size_t)min(max(zi, 0), DIN - 1) * (DIN * IRS);
      float4 pa[5], pb[5];
#pragma unroll
      for (int ky = 0; ky < 5; ++ky) {
        const float* row = pl + yoff[ky];
        pa[ky] = *(const float4*)(row + offA);
        pb[ky] = *(const float4*)(row + offB);
      }
      float pq[6][2];
#pragma unroll
      for (int qi = 0; qi < 6; ++qi) {
        pq[qi][0] = 0.f;
        pq[qi][1] = 0.f;
      }
#pragma unroll
      for (int ky = 0; ky < 5; ++ky) {
        float v[7] = {pa[ky].y, pa[ky].z, pa[ky].w, pb[ky].x, pb[ky].y, pb[ky].z, pb[ky].w};
        const bool yz = zok && yok[ky];
#pragma unroll
        for (int p = 0; p < 7; ++p) v[p] = (yz && xok[p]) ? v[p] : 0.f;
#pragma unroll
        for (int kx = 0; kx < 5; ++kx) {
          pq[QI(A2[ky] + A2[kx])][0] += v[kx];
          pq[QI(A2[ky] + A2[kx])][1] += v[2 + kx];
        }
      }
#pragma unroll
      for (int qi = 0; qi < 6; ++qi) {
        sg[GM[AZC][qi]][0] += pq[qi][0];
        sg[GM[AZC][qi]][1] += pq[qi][1];
      }
    };

    plane(std::integral_constant<int, 0>{}, 2);
#pragma unroll 1
    for (int rep = 0; rep < 2; ++rep) plane(std::integral_constant<int, 1>{}, 1 + 2 * rep);
#pragma unroll 1
    for (int rep = 0; rep < 2; ++rep) plane(std::integral_constant<int, 2>{}, 4 * rep);

    float z[3][2];
#pragma unroll
    for (int j = 0; j < 3; ++j) {
      z[j][0] = 0.f;
      z[j][1] = 0.f;
    }
#pragma unroll
    for (int gg = 0; gg < 10; ++gg) {
      const float4 bv4 = *(const float4*)&lbv[gg * 4];
#pragma unroll
      for (int n = 0; n < 2; ++n) {
        z[0][n] = fmaf(bv4.x, sg[gg][n], z[0][n]);
        z[1][n] = fmaf(bv4.y, sg[gg][n], z[1][n]);
        z[2][n] = fmaf(bv4.z, sg[gg][n], z[2][n]);
      }
    }
#pragma unroll
    for (int j = 0; j < 3; ++j) {
#pragma unroll
      for (int c4 = 0; c4 < C4N; ++c4) {
        const float4 w4 = *(const float4*)&lw[(icl * 3 + j) * CW + 4 * c4];
#pragma unroll
        for (int n = 0; n < 2; ++n) {
          acc[c4 * 4 + 0][n] = fmaf(w4.x, z[j][n], acc[c4 * 4 + 0][n]);
          acc[c4 * 4 + 1][n] = fmaf(w4.y, z[j][n], acc[c4 * 4 + 1][n]);
          acc[c4 * 4 + 2][n] = fmaf(w4.z, z[j][n], acc[c4 * 4 + 2][n]);
          acc[c4 * 4 + 3][n] = fmaf(w4.w, z[j][n], acc[c4 * 4 + 3][n]);
        }
      }
    }
  }

  if (!active) return;
  const int vbase = (zo * DOUT + yo) * ORS + xo0;

  if constexpr (EPI == 1) {
    float* __restrict__ op = out + (size_t)b * 20 * OSLAB + vbase;
#pragma unroll
    for (int n = 0; n < 2; ++n) {
      if (xo0 + n < DOUT) {
        const float g0 = 1.f / (1.f + expf(-acc[20][n]));
        const float g1 = 1.f / (1.f + expf(-acc[21][n]));
        const float g2 = 1.f / (1.f + expf(-acc[22][n]));
#pragma unroll
        for (int c = 0; c < 5; ++c) op[(size_t)c * OSLAB + n] = fmaxf(acc[c][n], 0.f);
#pragma unroll
        for (int c = 0; c < 3; ++c) op[(size_t)(5 + c) * OSLAB + n] = acc[5 + c][n] * g0;
#pragma unroll
        for (int c = 0; c < 5; ++c) op[(size_t)(8 + c) * OSLAB + n] = acc[8 + c][n] * g1;
#pragma unroll
        for (int c = 0; c < 7; ++c) op[(size_t)(13 + c) * OSLAB + n] = acc[13 + c][n] * g2;
      }
    }
  } else if constexpr (EPI == 0) {
    float* __restrict__ op = out + ((size_t)(g * BATCH + b) * OC) * OSLAB + vbase;
#pragma unroll
    for (int c = 0; c < CW; ++c) {
      if (c < OC) {
#pragma unroll
        for (int n = 0; n < 2; ++n)
          if (xo0 + n < DOUT) op[(size_t)c * OSLAB + n] = acc[c][n];
      }
    }
  } else {
    float* __restrict__ op = out + (size_t)b * OC * OSLAB + vbase;
#pragma unroll
    for (int c = 0; c < CW; ++c) {
      if (c < OC) {
#pragma unroll
        for (int n = 0; n < 2; ++n)
          if (xo0 + n < DOUT) op[(size_t)c * OSLAB + n] = acc[c][n];
      }
    }
  }
}

// conv2 with in-kernel spatial reduction: output only feeds AvgSpacial, so each
// block reduces its chunk and writes one 20-float partial: P2S[g][b][oc][chunk].
// DIN=18, DOUT=10, IRS=20, ICG=1, G=20, OC=20. Deterministic sum order.
__global__ __launch_bounds__(CTHREADS)
void conv2_red_kernel(const float* __restrict__ in, const float* __restrict__ W,
                      float* __restrict__ P2S) {
  constexpr int ICTOT = 20, OC = 20, CW = 20, DIN = 18, DOUT = 10, IRS = 20;
  constexpr int ISLAB = DIN * DIN * IRS;
  constexpr int XS = 5, SPI = DOUT * DOUT * XS, NB = 4, G = 20;

  __shared__ __align__(16) float lbv[40];
  __shared__ float lnrm[4];
  __shared__ __align__(16) float lw[3 * CW];
  __shared__ float red[2][20];

  const int bid = blockIdx.x;
  const int xcd = bid & 7;
  int slot = bid >> 3;
  const int chunk = slot % NB;
  slot /= NB;
  const int g = slot % G;
  const int bh = slot / G;
  const int b = xcd + 8 * bh;
  const int t = threadIdx.x;

  if (t < 40) {
    const int gc = t >> 2, j = t & 3;
    const float R2C[10] = {0.f, 1.f, 2.f, 3.f, 4.f, 5.f, 6.f, 8.f, 9.f, 12.f};
    float raw = 0.f;
    if (j < 3) {
      const float d = (sqrtf(R2C[gc]) - (float)j) * (1.0f / 0.6f);
      raw = expf(-0.5f * d * d);
    }
    lbv[t] = raw;
  }
  __syncthreads();
  if (t < 3) {
    const float MULT[10] = {1.f, 6.f, 12.f, 8.f, 6.f, 24.f, 24.f, 12.f, 24.f, 8.f};
    float ssum = 0.f;
    for (int gc = 0; gc < 10; ++gc) {
      const float v = lbv[gc * 4 + t];
      ssum += MULT[gc] * v * v;
    }
    lnrm[t] = rsqrtf(ssum);
  }
  __syncthreads();
  if (t < 40) lbv[t] = ((t & 3) < 3) ? lbv[t] * lnrm[t & 3] : 0.f;
  if (t < 3 * CW) {
    const int cc = t % CW, jj = t / CW;
    lw[jj * CW + cc] = W[((size_t)cc * ICTOT + g) * 3 + jj];
  }
  __syncthreads();

  const int s = chunk * CTHREADS + t;
  const bool active = s < SPI;
  const int si = active ? s : 0;
  const int zo = si / (DOUT * XS);
  const int yo = (si / XS) % DOUT;
  const int xo0 = (si % XS) * 2;

  float acc[CW][2];
#pragma unroll
  for (int c = 0; c < CW; ++c) {
    acc[c][0] = 0.f;
    acc[c][1] = 0.f;
  }

  const float* __restrict__ ipc = in + (size_t)(b * ICTOT + g) * ISLAB;
  const int offA = max(2 * xo0 - 4, 0);
  const int offB = min(2 * xo0, IRS - 4);
  bool xok[7];
#pragma unroll
  for (int p = 0; p < 7; ++p) xok[p] = (unsigned)(2 * xo0 - 3 + p) < (unsigned)DIN;
  int yoff[5];
  bool yok[5];
#pragma unroll
  for (int ky = 0; ky < 5; ++ky) {
    const int yi = 2 * yo - 3 + ky;
    yok[ky] = (unsigned)yi < (unsigned)DIN;
    yoff[ky] = min(max(yi, 0), DIN - 1) * IRS;
  }

  float sg[10][2];
#pragma unroll
  for (int gg = 0; gg < 10; ++gg) {
    sg[gg][0] = 0.f;
    sg[gg][1] = 0.f;
  }

  auto plane = [&](auto azc_c, int kz) {
    constexpr int AZC = decltype(azc_c)::value;
    constexpr int GM[3][6] = {
        {0, 1, 2, 4, 5, 7}, {1, 2, 3, 5, 6, 8}, {4, 5, 6, 7, 8, 9}};
    constexpr int A2[5] = {4, 1, 0, 1, 4};
    const int zi = 2 * zo - 3 + kz;
    const bool zok = (unsigned)zi < (unsigned)DIN;
    const float* pl = ipc + (size_t)min(max(zi, 0), DIN - 1) * (DIN * IRS);
    float4 pa[5], pb[5];
#pragma unroll
    for (int ky = 0; ky < 5; ++ky) {
      const float* row = pl + yoff[ky];
      pa[ky] = *(const float4*)(row + offA);
      pb[ky] = *(const float4*)(row + offB);
    }
    float pq[6][2];
#pragma unroll
    for (int qi = 0; qi < 6; ++qi) {
      pq[qi][0] = 0.f;
      pq[qi][1] = 0.f;
    }
#pragma unroll
    for (int ky = 0; ky < 5; ++ky) {
      float v[7] = {pa[ky].y, pa[ky].z, pa[ky].w, pb[ky].x, pb[ky].y, pb[ky].z, pb[ky].w};
      const bool yz = zok && yok[ky];
#pragma unroll
      for (int p = 0; p < 7; ++p) v[p] = (yz && xok[p]) ? v[p] : 0.f;
#pragma unroll
      for (int kx = 0; kx < 5; ++kx) {
        pq[QI(A2[ky] + A2[kx])][0] += v[kx];
        pq[QI(A2[ky] + A2[kx])][1] += v[2 + kx];
      }
    }
#pragma unroll
    for (int qi = 0; qi < 6; ++qi) {
      sg[GM[AZC][qi]][0] += pq[qi][0];
      sg[GM[AZC][qi]][1] += pq[qi][1];
    }
  };

  plane(std::integral_constant<int, 0>{}, 2);
#pragma unroll 1
  for (int rep = 0; rep < 2; ++rep) plane(std::integral_constant<int, 1>{}, 1 + 2 * rep);
#pragma unroll 1
  for (int rep = 0; rep < 2; ++rep) plane(std::integral_constant<int, 2>{}, 4 * rep);

  float z[3][2];
#pragma unroll
  for (int j = 0; j < 3; ++j) {
    z[j][0] = 0.f;
    z[j][1] = 0.f;
  }
#pragma unroll
  for (int gg = 0; gg < 10; ++gg) {
    const float4 bv4 = *(const float4*)&lbv[gg * 4];
#pragma unroll
    for (int n = 0; n < 2; ++n) {
      z[0][n] = fmaf(bv4.x, sg[gg][n], z[0][n]);
      z[1][n] = fmaf(bv4.y, sg[gg][n], z[1][n]);
      z[2][n] = fmaf(bv4.z, sg[gg][n], z[2][n]);
    }
  }
#pragma unroll
  for (int j = 0; j < 3; ++j) {
#pragma unroll
    for (int c4 = 0; c4 < 5; ++c4) {
      const float4 w4 = *(const float4*)&lw[j * CW + 4 * c4];
#pragma unroll
      for (int n = 0; n < 2; ++n) {
        acc[c4 * 4 + 0][n] = fmaf(w4.x, z[j][n], acc[c4 * 4 + 0][n]);
        acc[c4 * 4 + 1][n] = fmaf(w4.y, z[j][n], acc[c4 * 4 + 1][n]);
        acc[c4 * 4 + 2][n] = fmaf(w4.z, z[j][n], acc[c4 * 4 + 2][n]);
        acc[c4 * 4 + 3][n] = fmaf(w4.w, z[j][n], acc[c4 * 4 + 3][n]);
      }
    }
  }

  // block reduction (inactive threads contribute 0)
  float vsum[CW];
#pragma unroll
  for (int c = 0; c < CW; ++c)
    vsum[c] = active ? (acc[c][0] + acc[c][1]) : 0.f;
#pragma unroll
  for (int c = 0; c < CW; ++c) {
#pragma unroll
    for (int off = 32; off > 0; off >>= 1) vsum[c] += __shfl_down(vsum[c], off);
  }
  const int lane = t & 63, wv = t >> 6;
  if (lane == 0) {
#pragma unroll
    for (int c = 0; c < CW; ++c) red[wv][c] = vsum[c];
  }
  __syncthreads();
  if (t < CW)
    P2S[(((size_t)g * BATCH + b) * 20 + t) * 4 + chunk] = red[0][t] + red[1][t];
}

// Sum ic-group partials (23 ch, packed) + gating -> A1 padded (row stride 20).
template <int G>
__global__ __launch_bounds__(THREADS)
void combine_gate_kernel(const float* __restrict__ P, float* __restrict__ out) {
  const int tid = blockIdx.x * THREADS + threadIdx.x;
  if (tid >= BATCH * 5832) return;
  const int vox = tid % 5832;
  const int b = tid / 5832;
  float s[23];
#pragma unroll
  for (int oc = 0; oc < 23; ++oc) s[oc] = 0.f;
  for (int g = 0; g < G; ++g) {
    const float* __restrict__ p = P + ((size_t)(g * BATCH + b) * 23) * 5832 + vox;
#pragma unroll
    for (int oc = 0; oc < 23; ++oc) s[oc] += p[(size_t)oc * 5832];
  }
  const float g0 = 1.f / (1.f + expf(-s[20]));
  const float g1 = 1.f / (1.f + expf(-s[21]));
  const float g2 = 1.f / (1.f + expf(-s[22]));
  const int zz = vox / 324, yy = (vox / 18) % 18, xx = vox % 18;
  float* __restrict__ op = out + (size_t)b * 20 * 6480 + (zz * 18 + yy) * 20 + xx;
#pragma unroll
  for (int c = 0; c < 5; ++c) op[(size_t)c * 6480] = fmaxf(s[c], 0.f);
#pragma unroll
  for (int c = 0; c < 3; ++c) op[(size_t)(5 + c) * 6480] = s[5 + c] * g0;
#pragma unroll
  for (int c = 0; c < 5; ++c) op[(size_t)(8 + c) * 6480] = s[8 + c] * g1;
#pragma unroll
  for (int c = 0; c < 7; ++c) op[(size_t)(13 + c) * 6480] = s[13 + c] * g2;
}

// AvgSpacial (from P2S partial sums) + fc1(relu) + fc2, one block.
__global__ __launch_bounds__(THREADS)
void fc_kernel(const float* __restrict__ P2S,
               const float* __restrict__ fc1w, const float* __restrict__ fc1b,
               const float* __restrict__ fc2w, const float* __restrict__ fc2b,
               float* __restrict__ out) {
  const int t = threadIdx.x;
  __shared__ float xs[320];
  __shared__ float hh[800];
  for (int i = t; i < 320; i += THREADS) {
    const int b = i / 20, oc = i % 20;
    float s = 0.f;
    for (int g = 0; g < 20; ++g) {
      const float* p = P2S + (((size_t)g * BATCH + b) * 20 + oc) * 4;
      s += (p[0] + p[1]) + (p[2] + p[3]);
    }
    xs[i] = s * (1.0f / 1000.0f);
  }
  __syncthreads();
  for (int i = t; i < 800; i += THREADS) {
    const int b = i / 50, j = i % 50;
    float s = fc1b[j];
    for (int c = 0; c < 20; ++c) s += xs[b * 20 + c] * fc1w[j * 20 + c];
    hh[i] = fmaxf(s, 0.f);
  }
  __syncthreads();
  for (int i = t; i < 32; i += THREADS) {
    const int b = i / 2, k = i % 2;
    float s = fc2b[k];
    for (int j = 0; j < 50; ++j) s += hh[b * 50 + j] * fc2w[k * 50 + j];
    out[b * 2 + k] = s;
  }
}

extern "C" void kernel_launch(void* const* d_in, const int* in_sizes, int n_in,
                              void* d_out, int out_size, void* d_ws, size_t ws_size,
                              hipStream_t stream) {
  (void)in_sizes; (void)n_in; (void)out_size;
  const float* inp  = (const float*)d_in[0];
  const float* W0   = (const float*)d_in[1];
  const float* W1   = (const float*)d_in[2];
  const float* W2   = (const float*)d_in[3];
  const float* fc1w = (const float*)d_in[4];
  const float* fc1b = (const float*)d_in[5];
  const float* fc2w = (const float*)d_in[6];
  const float* fc2b = (const float*)d_in[7];
  float* out = (float*)d_out;

  float* ws = (float*)d_ws;
  float* A0  = ws;                       // 12,545,280 (padded rows 36)
  float* A1  = A0 + (size_t)12545280;    // 2,073,600  (padded rows 20)
  float* P2S = A1 + (size_t)2073600;     // 25,600
  float* P1  = P2S + 25600;              // variable

  const size_t favail = ws_size / 4;
  const size_t fixed = (size_t)12545280 + 2073600 + 25600;  // 14,644,480

  // conv0: SPI=18513, NB=145, grid 8*145*1*2 = 2320.
  hipLaunchKernelGGL((conv_kernel<1, 1, 23, 24, 64, 33, 64, 36, 6, 1>), dim3(2320),
                     dim3(CTHREADS), 0, stream, inp, W0, A0);

  if (favail >= fixed + (size_t)5 * BATCH * 23 * 5832) {
    // Tier A: conv1 G=5 (ICG=4), NB=23 -> grid 8*23*5*2 = 1840.
    hipLaunchKernelGGL((conv_kernel<20, 4, 23, 24, 33, 18, 36, 18, 6, 0>), dim3(1840),
                       dim3(CTHREADS), 0, stream, A0, W1, P1);
    hipLaunchKernelGGL((combine_gate_kernel<5>), dim3((16 * 5832 + THREADS - 1) / THREADS),
                       dim3(THREADS), 0, stream, P1, A1);
    hipLaunchKernelGGL(conv2_red_kernel, dim3(1280), dim3(CTHREADS), 0, stream, A1, W2, P2S);
    hipLaunchKernelGGL(fc_kernel, dim3(1), dim3(THREADS), 0, stream, P2S, fc1w, fc1b, fc2w, fc2b,
                       out);
  } else if (favail >= fixed + (size_t)2 * BATCH * 23 * 5832) {
    // Tier C: conv1 G=2 (ICG=10) -> grid 736.
    hipLaunchKernelGGL((conv_kernel<20, 10, 23, 24, 33, 18, 36, 18, 6, 0>), dim3(736),
                       dim3(CTHREADS), 0, stream, A0, W1, P1);
    hipLaunchKernelGGL((combine_gate_kernel<2>), dim3((16 * 5832 + THREADS - 1) / THREADS),
                       dim3(THREADS), 0, stream, P1, A1);
    hipLaunchKernelGGL(conv2_red_kernel, dim3(1280), dim3(CTHREADS), 0, stream, A1, W2, P2S);
    hipLaunchKernelGGL(fc_kernel, dim3(1), dim3(THREADS), 0, stream, P2S, fc1w, fc1b, fc2w, fc2b,
                       out);
  } else {
    // Tier D: fused fallback. conv1 gated -> A1 padded directly.
    hipLaunchKernelGGL((conv_kernel<20, 20, 23, 24, 33, 18, 36, 20, 6, 1>), dim3(368),
                       dim3(CTHREADS), 0, stream, A0, W1, A1);
    hipLaunchKernelGGL(conv2_red_kernel, dim3(1280), dim3(CTHREADS), 0, stream, A1, W2, P2S);
    hipLaunchKernelGGL(fc_kernel, dim3(1), dim3(THREADS), 0, stream, P2S, fc1w, fc1b, fc2w, fc2b,
                       out);
  }
}

// Round 12
// 94.178 us; speedup vs baseline: 1.1919x; 1.0610x over previous
//
#include <hip/hip_runtime.h>
#include <math.h>
#include <type_traits>

#define CTHREADS 256   // conv kernels (round 12: 128->256, block-slot occupancy)
#define THREADS 256    // aux kernels
constexpr int BATCH = 16;

// ---------------------------------------------------------------------------
// Radial-class conv (rounds 6-11) + round 12: 256-thread conv blocks. Round 11
// showed occupancy 15% vs 45% theoretical with 2-wave blocks -> block-slot
// concurrency per CU is the cap; 4-wave blocks double resident waves/CU.
//
// Workspace (floats):
//   A0 [16][20][33][33][36] : 12,545,280   (rows padded 33->36)
//   A1 [16][20][18][18][20] :  2,073,600   (rows padded 18->20)
//   P2S [20][16][20][2]     :     12,800
//   P1 [G1][16][23][5832]   (tier A G1=5: 10,730,880 -> 101.4 MB total)
// ---------------------------------------------------------------------------

__host__ __device__ constexpr int QI(int q) {  // q = ay^2+ax^2 in {0,1,2,4,5,8}
  return q == 0 ? 0 : q == 1 ? 1 : q == 2 ? 2 : q == 4 ? 3 : q == 5 ? 4 : 5;
}

// Direct conv via radial classes. Thread = 2 x-consecutive voxels, ALL OC
// channels of one ic-group. Block index XCD-pinned: bid&7 = xcd, b = xcd+8*bh.
// Per-block prologue synthesizes basis values + weight slice from W.
// EPI: 0 = partials [g][b][OC][vox] packed, 1 = gated 20ch, 2 = plain.
template <int ICTOT, int ICG, int OC, int OCP, int DIN, int DOUT, int IRS, int ORS,
          int C4N, int EPI>
__global__ __launch_bounds__(CTHREADS)
void conv_kernel(const float* __restrict__ in, const float* __restrict__ W,
                 float* __restrict__ out) {
  constexpr int G = ICTOT / ICG;
  constexpr int ISLAB = DIN * DIN * IRS;
  constexpr int OSLAB = DOUT * DOUT * ORS;
  constexpr int XS = (DOUT + 1) / 2;
  constexpr int SPI = DOUT * DOUT * XS;
  constexpr int NB = (SPI + CTHREADS - 1) / CTHREADS;
  constexpr int CW = C4N * 4;
  static_assert(CW == OCP, "full-width acc");

  __shared__ __align__(16) float lbv[40];
  __shared__ float lnrm[4];
  __shared__ __align__(16) float lw[ICG * 3 * CW];

  const int bid = blockIdx.x;
  const int xcd = bid & 7;
  int slot = bid >> 3;
  const int chunk = slot % NB;
  slot /= NB;
  const int g = slot % G;
  const int bh = slot / G;
  const int b = xcd + 8 * bh;
  const int t = threadIdx.x;

  // per-block basis synthesis
  if (t < 40) {
    const int gc = t >> 2, j = t & 3;
    const float R2C[10] = {0.f, 1.f, 2.f, 3.f, 4.f, 5.f, 6.f, 8.f, 9.f, 12.f};
    float raw = 0.f;
    if (j < 3) {
      const float d = (sqrtf(R2C[gc]) - (float)j) * (1.0f / 0.6f);
      raw = expf(-0.5f * d * d);
    }
    lbv[t] = raw;
  }
  __syncthreads();
  if (t < 3) {
    const float MULT[10] = {1.f, 6.f, 12.f, 8.f, 6.f, 24.f, 24.f, 12.f, 24.f, 8.f};
    float ssum = 0.f;
    for (int gc = 0; gc < 10; ++gc) {
      const float v = lbv[gc * 4 + t];
      ssum += MULT[gc] * v * v;
    }
    lnrm[t] = rsqrtf(ssum);
  }
  __syncthreads();
  if (t < 40) lbv[t] = ((t & 3) < 3) ? lbv[t] * lnrm[t & 3] : 0.f;
  for (int i = t; i < ICG * 3 * CW; i += CTHREADS) {
    const int cc = i % CW;
    const int jj = (i / CW) % 3;
    const int icl = i / (3 * CW);
    const int ic = g * ICG + icl;
    lw[i] = (cc < OC) ? W[((size_t)cc * ICTOT + ic) * 3 + jj] : 0.f;
  }
  __syncthreads();

  const int s = chunk * CTHREADS + t;
  const bool active = s < SPI;
  const int si = active ? s : 0;
  const int zo = si / (DOUT * XS);
  const int yo = (si / XS) % DOUT;
  const int xo0 = (si % XS) * 2;

  float acc[CW][2];
#pragma unroll
  for (int c = 0; c < CW; ++c) {
    acc[c][0] = 0.f;
    acc[c][1] = 0.f;
  }

  const float* __restrict__ ip0 = in + (size_t)(b * ICTOT + g * ICG) * ISLAB;
  const int offA = max(2 * xo0 - 4, 0);
  const int offB = min(2 * xo0, IRS - 4);
  bool xok[7];
#pragma unroll
  for (int p = 0; p < 7; ++p) xok[p] = (unsigned)(2 * xo0 - 3 + p) < (unsigned)DIN;
  int yoff[5];
  bool yok[5];
#pragma unroll
  for (int ky = 0; ky < 5; ++ky) {
    const int yi = 2 * yo - 3 + ky;
    yok[ky] = (unsigned)yi < (unsigned)DIN;
    yoff[ky] = min(max(yi, 0), DIN - 1) * IRS;
  }

#pragma unroll 1
  for (int icl = 0; icl < ICG; ++icl) {
    const float* __restrict__ ipc = ip0 + (size_t)icl * ISLAB;
    float sg[10][2];
#pragma unroll
    for (int gg = 0; gg < 10; ++gg) {
      sg[gg][0] = 0.f;
      sg[gg][1] = 0.f;
    }

    auto plane = [&](auto azc_c, int kz) {
      constexpr int AZC = decltype(azc_c)::value;
      constexpr int GM[3][6] = {
          {0, 1, 2, 4, 5, 7}, {1, 2, 3, 5, 6, 8}, {4, 5, 6, 7, 8, 9}};
      constexpr int A2[5] = {4, 1, 0, 1, 4};
      const int zi = 2 * zo - 3 + kz;
      const bool zok = (unsigned)zi < (unsigned)DIN;
      const float* pl = ipc + (size_t)min(max(zi, 0), DIN - 1) * (DIN * IRS);
      float4 pa[5], pb[5];
#pragma unroll
      for (int ky = 0; ky < 5; ++ky) {
        const float* row = pl + yoff[ky];
        pa[ky] = *(const float4*)(row + offA);
        pb[ky] = *(const float4*)(row + offB);
      }
      float pq[6][2];
#pragma unroll
      for (int qi = 0; qi < 6; ++qi) {
        pq[qi][0] = 0.f;
        pq[qi][1] = 0.f;
      }
#pragma unroll
      for (int ky = 0; ky < 5; ++ky) {
        float v[7] = {pa[ky].y, pa[ky].z, pa[ky].w, pb[ky].x, pb[ky].y, pb[ky].z, pb[ky].w};
        const bool yz = zok && yok[ky];
#pragma unroll
        for (int p = 0; p < 7; ++p) v[p] = (yz && xok[p]) ? v[p] : 0.f;
#pragma unroll
        for (int kx = 0; kx < 5; ++kx) {
          pq[QI(A2[ky] + A2[kx])][0] += v[kx];
          pq[QI(A2[ky] + A2[kx])][1] += v[2 + kx];
        }
      }
#pragma unroll
      for (int qi = 0; qi < 6; ++qi) {
        sg[GM[AZC][qi]][0] += pq[qi][0];
        sg[GM[AZC][qi]][1] += pq[qi][1];
      }
    };

    plane(std::integral_constant<int, 0>{}, 2);
#pragma unroll 1
    for (int rep = 0; rep < 2; ++rep) plane(std::integral_constant<int, 1>{}, 1 + 2 * rep);
#pragma unroll 1
    for (int rep = 0; rep < 2; ++rep) plane(std::integral_constant<int, 2>{}, 4 * rep);

    float z[3][2];
#pragma unroll
    for (int j = 0; j < 3; ++j) {
      z[j][0] = 0.f;
      z[j][1] = 0.f;
    }
#pragma unroll
    for (int gg = 0; gg < 10; ++gg) {
      const float4 bv4 = *(const float4*)&lbv[gg * 4];
#pragma unroll
      for (int n = 0; n < 2; ++n) {
        z[0][n] = fmaf(bv4.x, sg[gg][n], z[0][n]);
        z[1][n] = fmaf(bv4.y, sg[gg][n], z[1][n]);
        z[2][n] = fmaf(bv4.z, sg[gg][n], z[2][n]);
      }
    }
#pragma unroll
    for (int j = 0; j < 3; ++j) {
#pragma unroll
      for (int c4 = 0; c4 < C4N; ++c4) {
        const float4 w4 = *(const float4*)&lw[(icl * 3 + j) * CW + 4 * c4];
#pragma unroll
        for (int n = 0; n < 2; ++n) {
          acc[c4 * 4 + 0][n] = fmaf(w4.x, z[j][n], acc[c4 * 4 + 0][n]);
          acc[c4 * 4 + 1][n] = fmaf(w4.y, z[j][n], acc[c4 * 4 + 1][n]);
          acc[c4 * 4 + 2][n] = fmaf(w4.z, z[j][n], acc[c4 * 4 + 2][n]);
          acc[c4 * 4 + 3][n] = fmaf(w4.w, z[j][n], acc[c4 * 4 + 3][n]);
        }
      }
    }
  }

  if (!active) return;
  const int vbase = (zo * DOUT + yo) * ORS + xo0;

  if constexpr (EPI == 1) {
    float* __restrict__ op = out + (size_t)b * 20 * OSLAB + vbase;
#pragma unroll
    for (int n = 0; n < 2; ++n) {
      if (xo0 + n < DOUT) {
        const float g0 = 1.f / (1.f + expf(-acc[20][n]));
        const float g1 = 1.f / (1.f + expf(-acc[21][n]));
        const float g2 = 1.f / (1.f + expf(-acc[22][n]));
#pragma unroll
        for (int c = 0; c < 5; ++c) op[(size_t)c * OSLAB + n] = fmaxf(acc[c][n], 0.f);
#pragma unroll
        for (int c = 0; c < 3; ++c) op[(size_t)(5 + c) * OSLAB + n] = acc[5 + c][n] * g0;
#pragma unroll
        for (int c = 0; c < 5; ++c) op[(size_t)(8 + c) * OSLAB + n] = acc[8 + c][n] * g1;
#pragma unroll
        for (int c = 0; c < 7; ++c) op[(size_t)(13 + c) * OSLAB + n] = acc[13 + c][n] * g2;
      }
    }
  } else if constexpr (EPI == 0) {
    float* __restrict__ op = out + ((size_t)(g * BATCH + b) * OC) * OSLAB + vbase;
#pragma unroll
    for (int c = 0; c < CW; ++c) {
      if (c < OC) {
#pragma unroll
        for (int n = 0; n < 2; ++n)
          if (xo0 + n < DOUT) op[(size_t)c * OSLAB + n] = acc[c][n];
      }
    }
  } else {
    float* __restrict__ op = out + (size_t)b * OC * OSLAB + vbase;
#pragma unroll
    for (int c = 0; c < CW; ++c) {
      if (c < OC) {
#pragma unroll
        for (int n = 0; n < 2; ++n)
          if (xo0 + n < DOUT) op[(size_t)c * OSLAB + n] = acc[c][n];
      }
    }
  }
}

// conv2 with in-kernel spatial reduction -> P2S[g][b][oc][chunk], chunk in [0,2).
__global__ __launch_bounds__(CTHREADS)
void conv2_red_kernel(const float* __restrict__ in, const float* __restrict__ W,
                      float* __restrict__ P2S) {
  constexpr int ICTOT = 20, OC = 20, CW = 20, DIN = 18, DOUT = 10, IRS = 20;
  constexpr int ISLAB = DIN * DIN * IRS;
  constexpr int XS = 5, SPI = DOUT * DOUT * XS, NB = 2, G = 20;

  __shared__ __align__(16) float lbv[40];
  __shared__ float lnrm[4];
  __shared__ __align__(16) float lw[3 * CW];
  __shared__ float red[4][20];

  const int bid = blockIdx.x;
  const int xcd = bid & 7;
  int slot = bid >> 3;
  const int chunk = slot % NB;
  slot /= NB;
  const int g = slot % G;
  const int bh = slot / G;
  const int b = xcd + 8 * bh;
  const int t = threadIdx.x;

  if (t < 40) {
    const int gc = t >> 2, j = t & 3;
    const float R2C[10] = {0.f, 1.f, 2.f, 3.f, 4.f, 5.f, 6.f, 8.f, 9.f, 12.f};
    float raw = 0.f;
    if (j < 3) {
      const float d = (sqrtf(R2C[gc]) - (float)j) * (1.0f / 0.6f);
      raw = expf(-0.5f * d * d);
    }
    lbv[t] = raw;
  }
  __syncthreads();
  if (t < 3) {
    const float MULT[10] = {1.f, 6.f, 12.f, 8.f, 6.f, 24.f, 24.f, 12.f, 24.f, 8.f};
    float ssum = 0.f;
    for (int gc = 0; gc < 10; ++gc) {
      const float v = lbv[gc * 4 + t];
      ssum += MULT[gc] * v * v;
    }
    lnrm[t] = rsqrtf(ssum);
  }
  __syncthreads();
  if (t < 40) lbv[t] = ((t & 3) < 3) ? lbv[t] * lnrm[t & 3] : 0.f;
  if (t < 3 * CW) {
    const int cc = t % CW, jj = t / CW;
    lw[jj * CW + cc] = W[((size_t)cc * ICTOT + g) * 3 + jj];
  }
  __syncthreads();

  const int s = chunk * CTHREADS + t;
  const bool active = s < SPI;
  const int si = active ? s : 0;
  const int zo = si / (DOUT * XS);
  const int yo = (si / XS) % DOUT;
  const int xo0 = (si % XS) * 2;

  float acc[CW][2];
#pragma unroll
  for (int c = 0; c < CW; ++c) {
    acc[c][0] = 0.f;
    acc[c][1] = 0.f;
  }

  const float* __restrict__ ipc = in + (size_t)(b * ICTOT + g) * ISLAB;
  const int offA = max(2 * xo0 - 4, 0);
  const int offB = min(2 * xo0, IRS - 4);
  bool xok[7];
#pragma unroll
  for (int p = 0; p < 7; ++p) xok[p] = (unsigned)(2 * xo0 - 3 + p) < (unsigned)DIN;
  int yoff[5];
  bool yok[5];
#pragma unroll
  for (int ky = 0; ky < 5; ++ky) {
    const int yi = 2 * yo - 3 + ky;
    yok[ky] = (unsigned)yi < (unsigned)DIN;
    yoff[ky] = min(max(yi, 0), DIN - 1) * IRS;
  }

  float sg[10][2];
#pragma unroll
  for (int gg = 0; gg < 10; ++gg) {
    sg[gg][0] = 0.f;
    sg[gg][1] = 0.f;
  }

  auto plane = [&](auto azc_c, int kz) {
    constexpr int AZC = decltype(azc_c)::value;
    constexpr int GM[3][6] = {
        {0, 1, 2, 4, 5, 7}, {1, 2, 3, 5, 6, 8}, {4, 5, 6, 7, 8, 9}};
    constexpr int A2[5] = {4, 1, 0, 1, 4};
    const int zi = 2 * zo - 3 + kz;
    const bool zok = (unsigned)zi < (unsigned)DIN;
    const float* pl = ipc + (size_t)min(max(zi, 0), DIN - 1) * (DIN * IRS);
    float4 pa[5], pb[5];
#pragma unroll
    for (int ky = 0; ky < 5; ++ky) {
      const float* row = pl + yoff[ky];
      pa[ky] = *(const float4*)(row + offA);
      pb[ky] = *(const float4*)(row + offB);
    }
    float pq[6][2];
#pragma unroll
    for (int qi = 0; qi < 6; ++qi) {
      pq[qi][0] = 0.f;
      pq[qi][1] = 0.f;
    }
#pragma unroll
    for (int ky = 0; ky < 5; ++ky) {
      float v[7] = {pa[ky].y, pa[ky].z, pa[ky].w, pb[ky].x, pb[ky].y, pb[ky].z, pb[ky].w};
      const bool yz = zok && yok[ky];
#pragma unroll
      for (int p = 0; p < 7; ++p) v[p] = (yz && xok[p]) ? v[p] : 0.f;
#pragma unroll
      for (int kx = 0; kx < 5; ++kx) {
        pq[QI(A2[ky] + A2[kx])][0] += v[kx];
        pq[QI(A2[ky] + A2[kx])][1] += v[2 + kx];
      }
    }
#pragma unroll
    for (int qi = 0; qi < 6; ++qi) {
      sg[GM[AZC][qi]][0] += pq[qi][0];
      sg[GM[AZC][qi]][1] += pq[qi][1];
    }
  };

  plane(std::integral_constant<int, 0>{}, 2);
#pragma unroll 1
  for (int rep = 0; rep < 2; ++rep) plane(std::integral_constant<int, 1>{}, 1 + 2 * rep);
#pragma unroll 1
  for (int rep = 0; rep < 2; ++rep) plane(std::integral_constant<int, 2>{}, 4 * rep);

  float z[3][2];
#pragma unroll
  for (int j = 0; j < 3; ++j) {
    z[j][0] = 0.f;
    z[j][1] = 0.f;
  }
#pragma unroll
  for (int gg = 0; gg < 10; ++gg) {
    const float4 bv4 = *(const float4*)&lbv[gg * 4];
#pragma unroll
    for (int n = 0; n < 2; ++n) {
      z[0][n] = fmaf(bv4.x, sg[gg][n], z[0][n]);
      z[1][n] = fmaf(bv4.y, sg[gg][n], z[1][n]);
      z[2][n] = fmaf(bv4.z, sg[gg][n], z[2][n]);
    }
  }
#pragma unroll
  for (int j = 0; j < 3; ++j) {
#pragma unroll
    for (int c4 = 0; c4 < 5; ++c4) {
      const float4 w4 = *(const float4*)&lw[j * CW + 4 * c4];
#pragma unroll
      for (int n = 0; n < 2; ++n) {
        acc[c4 * 4 + 0][n] = fmaf(w4.x, z[j][n], acc[c4 * 4 + 0][n]);
        acc[c4 * 4 + 1][n] = fmaf(w4.y, z[j][n], acc[c4 * 4 + 1][n]);
        acc[c4 * 4 + 2][n] = fmaf(w4.z, z[j][n], acc[c4 * 4 + 2][n]);
        acc[c4 * 4 + 3][n] = fmaf(w4.w, z[j][n], acc[c4 * 4 + 3][n]);
      }
    }
  }

  float vsum[CW];
#pragma unroll
  for (int c = 0; c < CW; ++c)
    vsum[c] = active ? (acc[c][0] + acc[c][1]) : 0.f;
#pragma unroll
  for (int c = 0; c < CW; ++c) {
#pragma unroll
    for (int off = 32; off > 0; off >>= 1) vsum[c] += __shfl_down(vsum[c], off);
  }
  const int lane = t & 63, wv = t >> 6;
  if (lane == 0) {
#pragma unroll
    for (int c = 0; c < CW; ++c) red[wv][c] = vsum[c];
  }
  __syncthreads();
  if (t < CW)
    P2S[(((size_t)g * BATCH + b) * 20 + t) * 2 + chunk] =
        (red[0][t] + red[1][t]) + (red[2][t] + red[3][t]);
}

// Sum ic-group partials (23 ch, packed) + gating -> A1 padded. 2 voxels/thread.
template <int G>
__global__ __launch_bounds__(THREADS)
void combine_gate_kernel(const float* __restrict__ P, float* __restrict__ out) {
  const int tid = blockIdx.x * THREADS + threadIdx.x;
  if (tid >= BATCH * 2916) return;
  const int vp = tid % 2916;
  const int b = tid / 2916;
  const int vox = vp * 2;
  float s[23][2];
#pragma unroll
  for (int oc = 0; oc < 23; ++oc) s[oc][0] = s[oc][1] = 0.f;
  for (int g = 0; g < G; ++g) {
    const float* __restrict__ p = P + ((size_t)(g * BATCH + b) * 23) * 5832 + vox;
#pragma unroll
    for (int oc = 0; oc < 23; ++oc) {
      const float2 x = *(const float2*)(p + (size_t)oc * 5832);
      s[oc][0] += x.x;
      s[oc][1] += x.y;
    }
  }
  const int zz = vox / 324, yy = (vox / 18) % 18, xx = vox % 18;
  float* __restrict__ op = out + (size_t)b * 20 * 6480 + (zz * 18 + yy) * 20 + xx;
  float g0[2], g1[2], g2[2];
#pragma unroll
  for (int n = 0; n < 2; ++n) {
    g0[n] = 1.f / (1.f + expf(-s[20][n]));
    g1[n] = 1.f / (1.f + expf(-s[21][n]));
    g2[n] = 1.f / (1.f + expf(-s[22][n]));
  }
  float o[20][2];
#pragma unroll
  for (int c = 0; c < 5; ++c) { o[c][0] = fmaxf(s[c][0], 0.f); o[c][1] = fmaxf(s[c][1], 0.f); }
#pragma unroll
  for (int c = 0; c < 3; ++c) { o[5 + c][0] = s[5 + c][0] * g0[0]; o[5 + c][1] = s[5 + c][1] * g0[1]; }
#pragma unroll
  for (int c = 0; c < 5; ++c) { o[8 + c][0] = s[8 + c][0] * g1[0]; o[8 + c][1] = s[8 + c][1] * g1[1]; }
#pragma unroll
  for (int c = 0; c < 7; ++c) { o[13 + c][0] = s[13 + c][0] * g2[0]; o[13 + c][1] = s[13 + c][1] * g2[1]; }
#pragma unroll
  for (int c = 0; c < 20; ++c) *(float2*)(op + (size_t)c * 6480) = make_float2(o[c][0], o[c][1]);
}

// AvgSpacial (from P2S partial sums) + fc1(relu) + fc2, one block.
__global__ __launch_bounds__(THREADS)
void fc_kernel(const float* __restrict__ P2S,
               const float* __restrict__ fc1w, const float* __restrict__ fc1b,
               const float* __restrict__ fc2w, const float* __restrict__ fc2b,
               float* __restrict__ out) {
  const int t = threadIdx.x;
  __shared__ float xs[320];
  __shared__ float hh[800];
  for (int i = t; i < 320; i += THREADS) {
    const int b = i / 20, oc = i % 20;
    float s = 0.f;
    for (int g = 0; g < 20; ++g) {
      const float* p = P2S + (((size_t)g * BATCH + b) * 20 + oc) * 2;
      s += p[0] + p[1];
    }
    xs[i] = s * (1.0f / 1000.0f);
  }
  __syncthreads();
  for (int i = t; i < 800; i += THREADS) {
    const int b = i / 50, j = i % 50;
    float s = fc1b[j];
    for (int c = 0; c < 20; ++c) s += xs[b * 20 + c] * fc1w[j * 20 + c];
    hh[i] = fmaxf(s, 0.f);
  }
  __syncthreads();
  for (int i = t; i < 32; i += THREADS) {
    const int b = i / 2, k = i % 2;
    float s = fc2b[k];
    for (int j = 0; j < 50; ++j) s += hh[b * 50 + j] * fc2w[k * 50 + j];
    out[b * 2 + k] = s;
  }
}

extern "C" void kernel_launch(void* const* d_in, const int* in_sizes, int n_in,
                              void* d_out, int out_size, void* d_ws, size_t ws_size,
                              hipStream_t stream) {
  (void)in_sizes; (void)n_in; (void)out_size;
  const float* inp  = (const float*)d_in[0];
  const float* W0   = (const float*)d_in[1];
  const float* W1   = (const float*)d_in[2];
  const float* W2   = (const float*)d_in[3];
  const float* fc1w = (const float*)d_in[4];
  const float* fc1b = (const float*)d_in[5];
  const float* fc2w = (const float*)d_in[6];
  const float* fc2b = (const float*)d_in[7];
  float* out = (float*)d_out;

  float* ws = (float*)d_ws;
  float* A0  = ws;                       // 12,545,280 (padded rows 36)
  float* A1  = A0 + (size_t)12545280;    // 2,073,600  (padded rows 20)
  float* P2S = A1 + (size_t)2073600;     // 12,800
  float* P1  = P2S + 12800;              // variable

  const size_t favail = ws_size / 4;
  const size_t fixed = (size_t)12545280 + 2073600 + 12800;  // 14,631,680

  // conv0: SPI=18513, NB=73 -> grid 8*73*1*2 = 1168.
  hipLaunchKernelGGL((conv_kernel<1, 1, 23, 24, 64, 33, 64, 36, 6, 1>), dim3(1168),
                     dim3(CTHREADS), 0, stream, inp, W0, A0);

  if (favail >= fixed + (size_t)5 * BATCH * 23 * 5832) {
    // Tier A: conv1 G=5 (ICG=4), SPI=2916, NB=12 -> grid 8*12*5*2 = 960.
    hipLaunchKernelGGL((conv_kernel<20, 4, 23, 24, 33, 18, 36, 18, 6, 0>), dim3(960),
                       dim3(CTHREADS), 0, stream, A0, W1, P1);
    hipLaunchKernelGGL((combine_gate_kernel<5>), dim3((16 * 2916 + THREADS - 1) / THREADS),
                       dim3(THREADS), 0, stream, P1, A1);
    hipLaunchKernelGGL(conv2_red_kernel, dim3(640), dim3(CTHREADS), 0, stream, A1, W2, P2S);
    hipLaunchKernelGGL(fc_kernel, dim3(1), dim3(THREADS), 0, stream, P2S, fc1w, fc1b, fc2w, fc2b,
                       out);
  } else if (favail >= fixed + (size_t)2 * BATCH * 23 * 5832) {
    // Tier C: conv1 G=2 (ICG=10) -> grid 8*12*2*2 = 384.
    hipLaunchKernelGGL((conv_kernel<20, 10, 23, 24, 33, 18, 36, 18, 6, 0>), dim3(384),
                       dim3(CTHREADS), 0, stream, A0, W1, P1);
    hipLaunchKernelGGL((combine_gate_kernel<2>), dim3((16 * 2916 + THREADS - 1) / THREADS),
                       dim3(THREADS), 0, stream, P1, A1);
    hipLaunchKernelGGL(conv2_red_kernel, dim3(640), dim3(CTHREADS), 0, stream, A1, W2, P2S);
    hipLaunchKernelGGL(fc_kernel, dim3(1), dim3(THREADS), 0, stream, P2S, fc1w, fc1b, fc2w, fc2b,
                       out);
  } else {
    // Tier D: fused fallback. conv1 gated -> A1 padded directly.
    hipLaunchKernelGGL((conv_kernel<20, 20, 23, 24, 33, 18, 36, 20, 6, 1>), dim3(192),
                       dim3(CTHREADS), 0, stream, A0, W1, A1);
    hipLaunchKernelGGL(conv2_red_kernel, dim3(640), dim3(CTHREADS), 0, stream, A1, W2, P2S);
    hipLaunchKernelGGL(fc_kernel, dim3(1), dim3(THREADS), 0, stream, P2S, fc1w, fc1b, fc2w, fc2b,
                       out);
  }
}

// Round 14
// 88.567 us; speedup vs baseline: 1.2675x; 1.0634x over previous
//
#include <hip/hip_runtime.h>
#include <math.h>
#include <type_traits>

constexpr int BATCH = 16;

// ---------------------------------------------------------------------------
// Round 14: two-phase convs (round 13 design; OOB batch-decode FIXED:
// brel = (xcd % XB) + XB*slot with XB = min(NBH,8) — round 13 used NBH as the
// multiplier, computing b up to 23 -> memory fault).
// Phase A: tap sums -> z_j per (ic, voxel); small live set (no acc[24][2],
// pq folded into z per plane) -> high occupancy. Phase B: 23 x 3*IC channel
// mix + gating. conv2's mix commutes past AvgSpacial into fc_kernel.
//
// Workspace (floats):
//   A0 [16][20][33][33][36] : 12,545,280  (rows padded ->36)
//   A1 [16][20][18][18][20] :  2,073,600  (rows padded ->20; Z0 aliases this)
//   S  [16][60][2] (pad)    :      2,048
//   Z1 [16][60][5832]       :  5,598,720  (full; half/quarter tiers smaller)
// total full = 80.9 MB (proven ws >= 144.3 MB in round 10)
// ---------------------------------------------------------------------------

__host__ __device__ constexpr int QI(int q) {  // q = ay^2+ax^2 in {0,1,2,4,5,8}
  return q == 0 ? 0 : q == 1 ? 1 : q == 2 ? 2 : q == 4 ? 3 : q == 5 ? 4 : 5;
}

// Phase A: thread = 2 x-consecutive output voxels of ONE input channel.
// Computes z[3][2] radial projections of the 125 taps.
// MODE 0: write Z[brel][ic*3+j][vox] (packed DOUT^3).
// MODE 1: block-reduce sum over voxels -> S[((brel*ICT+ic)*3+j)*NB + chunk].
template <int ICT, int DIN, int DOUT, int IRS, int MODE, int NBH>
__global__ __launch_bounds__(256)
void convA_kernel(const float* __restrict__ in, float* __restrict__ outp, int bofs) {
  constexpr int ISLAB = DIN * DIN * IRS;
  constexpr int XS = (DOUT + 1) / 2;
  constexpr int SPI = DOUT * DOUT * XS;
  constexpr int NB = (SPI + 255) / 256;
  constexpr int DOUT3 = DOUT * DOUT * DOUT;
  constexpr int XB = (NBH < 8) ? NBH : 8;   // xcd slots used for batch
  static_assert(MODE == 0 || NB == 2, "S layout assumes 2 chunks");

  __shared__ __align__(16) float lbv[40];
  __shared__ float lnrm[4];
  __shared__ float red[4][3];

  const int bid = blockIdx.x;
  const int xcd = bid & 7;
  int slot = bid >> 3;
  const int chunk = slot % NB; slot /= NB;
  const int ic = slot % ICT;   slot /= ICT;   // slot = bh in [0, NBH/XB)
  const int brel = (xcd % XB) + XB * slot;    // in [0, NBH); XB<8 -> dup blocks, benign
  const int b = brel + bofs;
  const int t = threadIdx.x;

  // per-block radial basis synthesis (analytic class-multiplicity norm)
  if (t < 40) {
    const int gc = t >> 2, j = t & 3;
    const float R2C[10] = {0.f, 1.f, 2.f, 3.f, 4.f, 5.f, 6.f, 8.f, 9.f, 12.f};
    float raw = 0.f;
    if (j < 3) {
      const float d = (sqrtf(R2C[gc]) - (float)j) * (1.0f / 0.6f);
      raw = expf(-0.5f * d * d);
    }
    lbv[t] = raw;
  }
  __syncthreads();
  if (t < 3) {
    const float MULT[10] = {1.f, 6.f, 12.f, 8.f, 6.f, 24.f, 24.f, 12.f, 24.f, 8.f};
    float ssum = 0.f;
    for (int gc = 0; gc < 10; ++gc) {
      const float v = lbv[gc * 4 + t];
      ssum += MULT[gc] * v * v;
    }
    lnrm[t] = rsqrtf(ssum);
  }
  __syncthreads();
  if (t < 40) lbv[t] = ((t & 3) < 3) ? lbv[t] * lnrm[t & 3] : 0.f;
  __syncthreads();

  const int s = chunk * 256 + t;
  const bool active = s < SPI;
  const int si = active ? s : 0;
  const int zo = si / (DOUT * XS);
  const int yo = (si / XS) % DOUT;
  const int xo0 = (si % XS) * 2;

  const float* __restrict__ ipc = in + (size_t)(b * ICT + ic) * ISLAB;
  const int offA = max(2 * xo0 - 4, 0);
  const int offB = min(2 * xo0, IRS - 4);
  bool xok[7];
#pragma unroll
  for (int p = 0; p < 7; ++p) xok[p] = (unsigned)(2 * xo0 - 3 + p) < (unsigned)DIN;
  int yoff[5];
  bool yok[5];
#pragma unroll
  for (int ky = 0; ky < 5; ++ky) {
    const int yi = 2 * yo - 3 + ky;
    yok[ky] = (unsigned)yi < (unsigned)DIN;
    yoff[ky] = min(max(yi, 0), DIN - 1) * IRS;
  }

  float z[3][2];
#pragma unroll
  for (int j = 0; j < 3; ++j) { z[j][0] = 0.f; z[j][1] = 0.f; }

  auto plane = [&](auto azc_c, int kz) {
    constexpr int AZC = decltype(azc_c)::value;
    constexpr int GM[3][6] = {
        {0, 1, 2, 4, 5, 7}, {1, 2, 3, 5, 6, 8}, {4, 5, 6, 7, 8, 9}};
    constexpr int A2T[5] = {4, 1, 0, 1, 4};
    const int zi = 2 * zo - 3 + kz;
    const bool zok = (unsigned)zi < (unsigned)DIN;
    const float* pl = ipc + (size_t)min(max(zi, 0), DIN - 1) * (DIN * IRS);
    float4 pa[5], pb[5];
#pragma unroll
    for (int ky = 0; ky < 5; ++ky) {
      const float* row = pl + yoff[ky];
      pa[ky] = *(const float4*)(row + offA);
      pb[ky] = *(const float4*)(row + offB);
    }
    float pq[6][2];
#pragma unroll
    for (int qi = 0; qi < 6; ++qi) { pq[qi][0] = 0.f; pq[qi][1] = 0.f; }
#pragma unroll
    for (int ky = 0; ky < 5; ++ky) {
      float v[7] = {pa[ky].y, pa[ky].z, pa[ky].w, pb[ky].x, pb[ky].y, pb[ky].z, pb[ky].w};
      const bool yz = zok && yok[ky];
#pragma unroll
      for (int p = 0; p < 7; ++p) v[p] = (yz && xok[p]) ? v[p] : 0.f;
#pragma unroll
      for (int kx = 0; kx < 5; ++kx) {
        pq[QI(A2T[ky] + A2T[kx])][0] += v[kx];
        pq[QI(A2T[ky] + A2T[kx])][1] += v[2 + kx];
      }
    }
    // fold pq -> z directly (saves sg[10][2] registers)
#pragma unroll
    for (int qi = 0; qi < 6; ++qi) {
      const float4 bv4 = *(const float4*)&lbv[GM[AZC][qi] * 4];
#pragma unroll
      for (int n = 0; n < 2; ++n) {
        z[0][n] = fmaf(bv4.x, pq[qi][n], z[0][n]);
        z[1][n] = fmaf(bv4.y, pq[qi][n], z[1][n]);
        z[2][n] = fmaf(bv4.z, pq[qi][n], z[2][n]);
      }
    }
  };

  plane(std::integral_constant<int, 0>{}, 2);
#pragma unroll 1
  for (int rep = 0; rep < 2; ++rep) plane(std::integral_constant<int, 1>{}, 1 + 2 * rep);
#pragma unroll 1
  for (int rep = 0; rep < 2; ++rep) plane(std::integral_constant<int, 2>{}, 4 * rep);

  if constexpr (MODE == 0) {
    if (!active) return;
    const int vbase = (zo * DOUT + yo) * DOUT + xo0;
    float* __restrict__ zp = outp + ((size_t)(brel * ICT + ic) * 3) * DOUT3 + vbase;
#pragma unroll
    for (int j = 0; j < 3; ++j) {
      zp[(size_t)j * DOUT3] = z[j][0];
      if (xo0 + 1 < DOUT) zp[(size_t)j * DOUT3 + 1] = z[j][1];
    }
  } else {
    float v3[3];
#pragma unroll
    for (int j = 0; j < 3; ++j) v3[j] = active ? (z[j][0] + z[j][1]) : 0.f;
#pragma unroll
    for (int j = 0; j < 3; ++j) {
#pragma unroll
      for (int off = 32; off > 0; off >>= 1) v3[j] += __shfl_down(v3[j], off);
    }
    const int lane = t & 63, wv = t >> 6;
    if (lane == 0) {
#pragma unroll
      for (int j = 0; j < 3; ++j) red[wv][j] = v3[j];
    }
    __syncthreads();
    if (t < 3)
      outp[((size_t)(brel * ICT + ic) * 3 + t) * NB + chunk] =
          (red[0][t] + red[1][t]) + (red[2][t] + red[3][t]);
  }
}

// Phase B: channel mix (23 out-ch from K=3*ICT z-features) + capsule gating.
// Thread = 1 voxel. Writes 20 channels, padded row stride ORS.
template <int K, int DOUT, int ORS, int NBH>
__global__ __launch_bounds__(128)
void convB_kernel(const float* __restrict__ Z, const float* __restrict__ W,
                  float* __restrict__ out) {
  constexpr int ICT = K / 3;
  constexpr int DOUT3 = DOUT * DOUT * DOUT;
  constexpr int OSLAB = DOUT * DOUT * ORS;

  __shared__ __align__(16) float lw[K * 24];
  const int t = threadIdx.x;
  for (int i = t; i < K * 24; i += 128) {
    const int oc = i % 24, k = i / 24, icc = k / 3, jj = k % 3;
    lw[i] = (oc < 23) ? W[((size_t)oc * ICT + icc) * 3 + jj] : 0.f;
  }
  __syncthreads();

  const int gv = blockIdx.x * 128 + t;
  if (gv >= NBH * DOUT3) return;
  const int b = gv / DOUT3;
  const int vox = gv % DOUT3;

  float acc[24];
#pragma unroll
  for (int c = 0; c < 24; ++c) acc[c] = 0.f;

  const float* __restrict__ zp = Z + (size_t)b * K * DOUT3 + vox;
#pragma unroll 10
  for (int k = 0; k < K; ++k) {
    const float zv = zp[(size_t)k * DOUT3];
#pragma unroll
    for (int c4 = 0; c4 < 6; ++c4) {
      const float4 w4 = *(const float4*)&lw[k * 24 + 4 * c4];
      acc[c4 * 4 + 0] = fmaf(w4.x, zv, acc[c4 * 4 + 0]);
      acc[c4 * 4 + 1] = fmaf(w4.y, zv, acc[c4 * 4 + 1]);
      acc[c4 * 4 + 2] = fmaf(w4.z, zv, acc[c4 * 4 + 2]);
      acc[c4 * 4 + 3] = fmaf(w4.w, zv, acc[c4 * 4 + 3]);
    }
  }

  const int zz = vox / (DOUT * DOUT), yy = (vox / DOUT) % DOUT, xx = vox % DOUT;
  float* __restrict__ op = out + (size_t)b * 20 * OSLAB + (zz * DOUT + yy) * ORS + xx;
  const float g0 = 1.f / (1.f + expf(-acc[20]));
  const float g1 = 1.f / (1.f + expf(-acc[21]));
  const float g2 = 1.f / (1.f + expf(-acc[22]));
#pragma unroll
  for (int c = 0; c < 5; ++c) op[(size_t)c * OSLAB] = fmaxf(acc[c], 0.f);
#pragma unroll
  for (int c = 0; c < 3; ++c) op[(size_t)(5 + c) * OSLAB] = acc[5 + c] * g0;
#pragma unroll
  for (int c = 0; c < 5; ++c) op[(size_t)(8 + c) * OSLAB] = acc[8 + c] * g1;
#pragma unroll
  for (int c = 0; c < 7; ++c) op[(size_t)(13 + c) * OSLAB] = acc[13 + c] * g2;
}

// conv2 channel-mix (commuted past AvgSpacial) + fc1(relu) + fc2, one block.
// xs[b][oc] = (1/1000) * sum_k W2[oc*60+k] * (S[b][k][0]+S[b][k][1])
__global__ __launch_bounds__(256)
void fc_kernel(const float* __restrict__ S, const float* __restrict__ W2,
               const float* __restrict__ fc1w, const float* __restrict__ fc1b,
               const float* __restrict__ fc2w, const float* __restrict__ fc2b,
               float* __restrict__ out) {
  const int t = threadIdx.x;
  __shared__ float SB[960];
  __shared__ float xs[320];
  __shared__ float hh[800];
  for (int i = t; i < 960; i += 256)
    SB[i] = S[(size_t)i * 2] + S[(size_t)i * 2 + 1];  // i = b*60+k
  __syncthreads();
  for (int i = t; i < 320; i += 256) {
    const int b = i / 20, oc = i % 20;
    float s = 0.f;
    for (int k = 0; k < 60; ++k) s += W2[oc * 60 + k] * SB[b * 60 + k];
    xs[i] = s * (1.0f / 1000.0f);
  }
  __syncthreads();
  for (int i = t; i < 800; i += 256) {
    const int b = i / 50, j = i % 50;
    float s = fc1b[j];
    for (int c = 0; c < 20; ++c) s += xs[b * 20 + c] * fc1w[j * 20 + c];
    hh[i] = fmaxf(s, 0.f);
  }
  __syncthreads();
  for (int i = t; i < 32; i += 256) {
    const int b = i / 2, k = i % 2;
    float s = fc2b[k];
    for (int j = 0; j < 50; ++j) s += hh[b * 50 + j] * fc2w[k * 50 + j];
    out[b * 2 + k] = s;
  }
}

extern "C" void kernel_launch(void* const* d_in, const int* in_sizes, int n_in,
                              void* d_out, int out_size, void* d_ws, size_t ws_size,
                              hipStream_t stream) {
  (void)in_sizes; (void)n_in; (void)out_size;
  const float* inp  = (const float*)d_in[0];
  const float* W0   = (const float*)d_in[1];
  const float* W1   = (const float*)d_in[2];
  const float* W2   = (const float*)d_in[3];
  const float* fc1w = (const float*)d_in[4];
  const float* fc1b = (const float*)d_in[5];
  const float* fc2w = (const float*)d_in[6];
  const float* fc2b = (const float*)d_in[7];
  float* out = (float*)d_out;

  float* ws = (float*)d_ws;
  float* A0 = ws;                      // 12,545,280
  float* A1 = A0 + (size_t)12545280;   // 2,073,600 (Z0 = 1,724,976 aliases this)
  float* Z0 = A1;
  float* S  = A1 + (size_t)2073600;    // 2048 (uses 1920)
  float* Z1 = S + 2048;                // variable

  const size_t favail = ws_size / 4;
  const size_t base = (size_t)12545280 + 2073600 + 2048;  // 14,620,928

  // conv0 phase A: inp -> Z0[16][3][35937]. grid 8*73*1*2 = 1168.
  hipLaunchKernelGGL((convA_kernel<1, 64, 33, 64, 0, 16>), dim3(1168), dim3(256), 0, stream,
                     inp, Z0, 0);
  // conv0 phase B: Z0 -> A0 (gated, padded 36). 16*35937/128 -> 4493 blocks.
  hipLaunchKernelGGL((convB_kernel<3, 33, 36, 16>), dim3(4493), dim3(128), 0, stream,
                     Z0, W0, A0);

  if (favail >= base + (size_t)16 * 60 * 5832) {
    // full: conv1 A: A0 -> Z1[16][60][5832]. grid 8*12*20*2 = 3840.
    hipLaunchKernelGGL((convA_kernel<20, 33, 18, 36, 0, 16>), dim3(3840), dim3(256), 0, stream,
                       A0, Z1, 0);
    // conv1 B: Z1 -> A1 (gated, padded 20). 16*5832/128 -> 729 blocks.
    hipLaunchKernelGGL((convB_kernel<60, 18, 20, 16>), dim3(729), dim3(128), 0, stream,
                       Z1, W1, A1);
  } else if (favail >= base + (size_t)8 * 60 * 5832) {
    for (int h = 0; h < 2; ++h) {
      hipLaunchKernelGGL((convA_kernel<20, 33, 18, 36, 0, 8>), dim3(1920), dim3(256), 0, stream,
                         A0, Z1, 8 * h);
      hipLaunchKernelGGL((convB_kernel<60, 18, 20, 8>), dim3(365), dim3(128), 0, stream,
                         Z1, W1, A1 + (size_t)8 * h * 20 * 6480);
    }
  } else {
    for (int h = 0; h < 4; ++h) {
      hipLaunchKernelGGL((convA_kernel<20, 33, 18, 36, 0, 4>), dim3(1920), dim3(256), 0, stream,
                         A0, Z1, 4 * h);
      hipLaunchKernelGGL((convB_kernel<60, 18, 20, 4>), dim3(183), dim3(128), 0, stream,
                         Z1, W1, A1 + (size_t)4 * h * 20 * 6480);
    }
  }

  // conv2 phase A + spatial reduce: A1 -> S[16][60][2]. grid 8*2*20*2 = 640.
  hipLaunchKernelGGL((convA_kernel<20, 18, 10, 20, 1, 16>), dim3(640), dim3(256), 0, stream,
                     A1, S, 0);
  // conv2 mix (commuted) + fc.
  hipLaunchKernelGGL(fc_kernel, dim3(1), dim3(256), 0, stream, S, W2, fc1w, fc1b, fc2w, fc2b,
                     out);
}

// Round 15
// 82.607 us; speedup vs baseline: 1.3589x; 1.0721x over previous
//
#include <hip/hip_runtime.h>
#include <math.h>
#include <type_traits>

constexpr int BATCH = 16;

// ---------------------------------------------------------------------------
// Round 15: conv0 phases re-fused. conv0 has ICT=1, so its "phase B" was a
// trivial K=3 mix — now an epilogue of phase A (z[3][2] is the only hot-loop
// accumulator; the 23-ch mix materializes per-voxel in the epilogue only).
// Saves the Z0 write+read (14 MB) and one dispatch. conv1 stays two-phase
// (K=60 mix genuinely needs the split); conv2 phase A block-reduces to S;
// conv2's mix commutes past AvgSpacial into fc_kernel.
//
// Workspace (floats):
//   A0 [16][20][33][33][36] : 12,545,280  (rows padded ->36)
//   A1 [16][20][18][18][20] :  2,073,600  (rows padded ->20)
//   S  [16][60][2] (pad)    :      2,048
//   Z1 [16][60][5832]       :  5,598,720  (full; half/quarter tiers smaller)
// ---------------------------------------------------------------------------

__host__ __device__ constexpr int QI(int q) {  // q = ay^2+ax^2 in {0,1,2,4,5,8}
  return q == 0 ? 0 : q == 1 ? 1 : q == 2 ? 2 : q == 4 ? 3 : q == 5 ? 4 : 5;
}

// Shared per-block radial-basis synthesis: lbv[40] = B_j value per r^2-class
// (4-padded), normalized analytically via class multiplicities.
__device__ __forceinline__ void synth_basis(float* lbv, float* lnrm, int t) {
  if (t < 40) {
    const int gc = t >> 2, j = t & 3;
    const float R2C[10] = {0.f, 1.f, 2.f, 3.f, 4.f, 5.f, 6.f, 8.f, 9.f, 12.f};
    float raw = 0.f;
    if (j < 3) {
      const float d = (sqrtf(R2C[gc]) - (float)j) * (1.0f / 0.6f);
      raw = expf(-0.5f * d * d);
    }
    lbv[t] = raw;
  }
  __syncthreads();
  if (t < 3) {
    const float MULT[10] = {1.f, 6.f, 12.f, 8.f, 6.f, 24.f, 24.f, 12.f, 24.f, 8.f};
    float ssum = 0.f;
    for (int gc = 0; gc < 10; ++gc) {
      const float v = lbv[gc * 4 + t];
      ssum += MULT[gc] * v * v;
    }
    lnrm[t] = rsqrtf(ssum);
  }
  __syncthreads();
  if (t < 40) lbv[t] = ((t & 3) < 3) ? lbv[t] * lnrm[t & 3] : 0.f;
  __syncthreads();
}

// The radial tap-sum core: computes z[3][2] for a 2-voxel strip of one input
// channel. Shared by all conv kernels.
template <int DIN, int DOUT, int IRS>
__device__ __forceinline__ void radial_z(const float* __restrict__ ipc,
                                         const float* __restrict__ lbv,
                                         int zo, int yo, int xo0,
                                         const bool* xok, const int* yoff,
                                         const bool* yok, int offA, int offB,
                                         float (&z)[3][2]) {
#pragma unroll
  for (int j = 0; j < 3; ++j) { z[j][0] = 0.f; z[j][1] = 0.f; }

  auto plane = [&](auto azc_c, int kz) {
    constexpr int AZC = decltype(azc_c)::value;
    constexpr int GM[3][6] = {
        {0, 1, 2, 4, 5, 7}, {1, 2, 3, 5, 6, 8}, {4, 5, 6, 7, 8, 9}};
    constexpr int A2T[5] = {4, 1, 0, 1, 4};
    const int zi = 2 * zo - 3 + kz;
    const bool zok = (unsigned)zi < (unsigned)DIN;
    const float* pl = ipc + (size_t)min(max(zi, 0), DIN - 1) * (DIN * IRS);
    float4 pa[5], pb[5];
#pragma unroll
    for (int ky = 0; ky < 5; ++ky) {
      const float* row = pl + yoff[ky];
      pa[ky] = *(const float4*)(row + offA);
      pb[ky] = *(const float4*)(row + offB);
    }
    float pq[6][2];
#pragma unroll
    for (int qi = 0; qi < 6; ++qi) { pq[qi][0] = 0.f; pq[qi][1] = 0.f; }
#pragma unroll
    for (int ky = 0; ky < 5; ++ky) {
      float v[7] = {pa[ky].y, pa[ky].z, pa[ky].w, pb[ky].x, pb[ky].y, pb[ky].z, pb[ky].w};
      const bool yz = zok && yok[ky];
#pragma unroll
      for (int p = 0; p < 7; ++p) v[p] = (yz && xok[p]) ? v[p] : 0.f;
#pragma unroll
      for (int kx = 0; kx < 5; ++kx) {
        pq[QI(A2T[ky] + A2T[kx])][0] += v[kx];
        pq[QI(A2T[ky] + A2T[kx])][1] += v[2 + kx];
      }
    }
#pragma unroll
    for (int qi = 0; qi < 6; ++qi) {
      const float4 bv4 = *(const float4*)&lbv[GM[AZC][qi] * 4];
#pragma unroll
      for (int n = 0; n < 2; ++n) {
        z[0][n] = fmaf(bv4.x, pq[qi][n], z[0][n]);
        z[1][n] = fmaf(bv4.y, pq[qi][n], z[1][n]);
        z[2][n] = fmaf(bv4.z, pq[qi][n], z[2][n]);
      }
    }
  };

  plane(std::integral_constant<int, 0>{}, 2);
#pragma unroll 1
  for (int rep = 0; rep < 2; ++rep) plane(std::integral_constant<int, 1>{}, 1 + 2 * rep);
#pragma unroll 1
  for (int rep = 0; rep < 2; ++rep) plane(std::integral_constant<int, 2>{}, 4 * rep);
}

// conv0 fused: ICT=1, so tap-sum -> z[3][2] -> 23x3 mix + gate in epilogue.
// in: [16][64^3] packed, out: A0 [16][20][33][33][36].
__global__ __launch_bounds__(256)
void conv0_kernel(const float* __restrict__ in, const float* __restrict__ W0,
                  float* __restrict__ out) {
  constexpr int DIN = 64, DOUT = 33, IRS = 64, ORS = 36;
  constexpr int ISLAB = DIN * DIN * IRS;
  constexpr int OSLAB = DOUT * DOUT * ORS;
  constexpr int XS = 17, SPI = DOUT * DOUT * XS, NB = (SPI + 255) / 256;

  __shared__ __align__(16) float lbv[40];
  __shared__ float lnrm[4];
  __shared__ __align__(16) float lw[3 * 24];

  const int bid = blockIdx.x;
  const int xcd = bid & 7;
  int slot = bid >> 3;
  const int chunk = slot % NB; slot /= NB;
  const int b = xcd + 8 * slot;  // slot in [0,2)
  const int t = threadIdx.x;

  synth_basis(lbv, lnrm, t);
  if (t < 72) {
    const int oc = t % 24, j = t / 24;
    lw[t] = (oc < 23) ? W0[oc * 3 + j] : 0.f;
  }
  __syncthreads();

  const int s = chunk * 256 + t;
  const bool active = s < SPI;
  const int si = active ? s : 0;
  const int zo = si / (DOUT * XS);
  const int yo = (si / XS) % DOUT;
  const int xo0 = (si % XS) * 2;

  const float* __restrict__ ipc = in + (size_t)b * ISLAB;
  const int offA = max(2 * xo0 - 4, 0);
  const int offB = min(2 * xo0, IRS - 4);
  bool xok[7];
#pragma unroll
  for (int p = 0; p < 7; ++p) xok[p] = (unsigned)(2 * xo0 - 3 + p) < (unsigned)DIN;
  int yoff[5];
  bool yok[5];
#pragma unroll
  for (int ky = 0; ky < 5; ++ky) {
    const int yi = 2 * yo - 3 + ky;
    yok[ky] = (unsigned)yi < (unsigned)DIN;
    yoff[ky] = min(max(yi, 0), DIN - 1) * IRS;
  }

  float z[3][2];
  radial_z<DIN, DOUT, IRS>(ipc, lbv, zo, yo, xo0, xok, yoff, yok, offA, offB, z);

  if (!active) return;
  float* __restrict__ op = out + (size_t)b * 20 * OSLAB + (zo * DOUT + yo) * ORS + xo0;
#pragma unroll
  for (int n = 0; n < 2; ++n) {
    if (xo0 + n < DOUT) {
      float acc[24];
#pragma unroll
      for (int c4 = 0; c4 < 6; ++c4) {
        const float4 w0 = *(const float4*)&lw[0 * 24 + 4 * c4];
        const float4 w1 = *(const float4*)&lw[1 * 24 + 4 * c4];
        const float4 w2 = *(const float4*)&lw[2 * 24 + 4 * c4];
        acc[c4 * 4 + 0] = w0.x * z[0][n] + w1.x * z[1][n] + w2.x * z[2][n];
        acc[c4 * 4 + 1] = w0.y * z[0][n] + w1.y * z[1][n] + w2.y * z[2][n];
        acc[c4 * 4 + 2] = w0.z * z[0][n] + w1.z * z[1][n] + w2.z * z[2][n];
        acc[c4 * 4 + 3] = w0.w * z[0][n] + w1.w * z[1][n] + w2.w * z[2][n];
      }
      const float g0 = 1.f / (1.f + expf(-acc[20]));
      const float g1 = 1.f / (1.f + expf(-acc[21]));
      const float g2 = 1.f / (1.f + expf(-acc[22]));
#pragma unroll
      for (int c = 0; c < 5; ++c) op[(size_t)c * OSLAB + n] = fmaxf(acc[c], 0.f);
#pragma unroll
      for (int c = 0; c < 3; ++c) op[(size_t)(5 + c) * OSLAB + n] = acc[5 + c] * g0;
#pragma unroll
      for (int c = 0; c < 5; ++c) op[(size_t)(8 + c) * OSLAB + n] = acc[8 + c] * g1;
#pragma unroll
      for (int c = 0; c < 7; ++c) op[(size_t)(13 + c) * OSLAB + n] = acc[13 + c] * g2;
    }
  }
}

// conv1/conv2 phase A: z per (ic, 2-voxel strip).
// MODE 0: write Z[brel][ic*3+j][vox]; MODE 1: block-reduce -> S[..][chunk].
template <int ICT, int DIN, int DOUT, int IRS, int MODE, int NBH>
__global__ __launch_bounds__(256)
void convA_kernel(const float* __restrict__ in, float* __restrict__ outp, int bofs) {
  constexpr int ISLAB = DIN * DIN * IRS;
  constexpr int XS = (DOUT + 1) / 2;
  constexpr int SPI = DOUT * DOUT * XS;
  constexpr int NB = (SPI + 255) / 256;
  constexpr int DOUT3 = DOUT * DOUT * DOUT;
  constexpr int XB = (NBH < 8) ? NBH : 8;
  static_assert(MODE == 0 || NB == 2, "S layout assumes 2 chunks");

  __shared__ __align__(16) float lbv[40];
  __shared__ float lnrm[4];
  __shared__ float red[4][3];

  const int bid = blockIdx.x;
  const int xcd = bid & 7;
  int slot = bid >> 3;
  const int chunk = slot % NB; slot /= NB;
  const int ic = slot % ICT;   slot /= ICT;
  const int brel = (xcd % XB) + XB * slot;
  const int b = brel + bofs;
  const int t = threadIdx.x;

  synth_basis(lbv, lnrm, t);

  const int s = chunk * 256 + t;
  const bool active = s < SPI;
  const int si = active ? s : 0;
  const int zo = si / (DOUT * XS);
  const int yo = (si / XS) % DOUT;
  const int xo0 = (si % XS) * 2;

  const float* __restrict__ ipc = in + (size_t)(b * ICT + ic) * ISLAB;
  const int offA = max(2 * xo0 - 4, 0);
  const int offB = min(2 * xo0, IRS - 4);
  bool xok[7];
#pragma unroll
  for (int p = 0; p < 7; ++p) xok[p] = (unsigned)(2 * xo0 - 3 + p) < (unsigned)DIN;
  int yoff[5];
  bool yok[5];
#pragma unroll
  for (int ky = 0; ky < 5; ++ky) {
    const int yi = 2 * yo - 3 + ky;
    yok[ky] = (unsigned)yi < (unsigned)DIN;
    yoff[ky] = min(max(yi, 0), DIN - 1) * IRS;
  }

  float z[3][2];
  radial_z<DIN, DOUT, IRS>(ipc, lbv, zo, yo, xo0, xok, yoff, yok, offA, offB, z);

  if constexpr (MODE == 0) {
    if (!active) return;
    const int vbase = (zo * DOUT + yo) * DOUT + xo0;
    float* __restrict__ zp = outp + ((size_t)(brel * ICT + ic) * 3) * DOUT3 + vbase;
#pragma unroll
    for (int j = 0; j < 3; ++j) {
      zp[(size_t)j * DOUT3] = z[j][0];
      if (xo0 + 1 < DOUT) zp[(size_t)j * DOUT3 + 1] = z[j][1];
    }
  } else {
    float v3[3];
#pragma unroll
    for (int j = 0; j < 3; ++j) v3[j] = active ? (z[j][0] + z[j][1]) : 0.f;
#pragma unroll
    for (int j = 0; j < 3; ++j) {
#pragma unroll
      for (int off = 32; off > 0; off >>= 1) v3[j] += __shfl_down(v3[j], off);
    }
    const int lane = t & 63, wv = t >> 6;
    if (lane == 0) {
#pragma unroll
      for (int j = 0; j < 3; ++j) red[wv][j] = v3[j];
    }
    __syncthreads();
    if (t < 3)
      outp[((size_t)(brel * ICT + ic) * 3 + t) * NB + chunk] =
          (red[0][t] + red[1][t]) + (red[2][t] + red[3][t]);
  }
}

// Phase B: channel mix (23 out-ch from K z-features) + capsule gating.
template <int K, int DOUT, int ORS, int NBH>
__global__ __launch_bounds__(128)
void convB_kernel(const float* __restrict__ Z, const float* __restrict__ W,
                  float* __restrict__ out) {
  constexpr int ICT = K / 3;
  constexpr int DOUT3 = DOUT * DOUT * DOUT;
  constexpr int OSLAB = DOUT * DOUT * ORS;

  __shared__ __align__(16) float lw[K * 24];
  const int t = threadIdx.x;
  for (int i = t; i < K * 24; i += 128) {
    const int oc = i % 24, k = i / 24, icc = k / 3, jj = k % 3;
    lw[i] = (oc < 23) ? W[((size_t)oc * ICT + icc) * 3 + jj] : 0.f;
  }
  __syncthreads();

  const int gv = blockIdx.x * 128 + t;
  if (gv >= NBH * DOUT3) return;
  const int b = gv / DOUT3;
  const int vox = gv % DOUT3;

  float acc[24];
#pragma unroll
  for (int c = 0; c < 24; ++c) acc[c] = 0.f;

  const float* __restrict__ zp = Z + (size_t)b * K * DOUT3 + vox;
#pragma unroll 10
  for (int k = 0; k < K; ++k) {
    const float zv = zp[(size_t)k * DOUT3];
#pragma unroll
    for (int c4 = 0; c4 < 6; ++c4) {
      const float4 w4 = *(const float4*)&lw[k * 24 + 4 * c4];
      acc[c4 * 4 + 0] = fmaf(w4.x, zv, acc[c4 * 4 + 0]);
      acc[c4 * 4 + 1] = fmaf(w4.y, zv, acc[c4 * 4 + 1]);
      acc[c4 * 4 + 2] = fmaf(w4.z, zv, acc[c4 * 4 + 2]);
      acc[c4 * 4 + 3] = fmaf(w4.w, zv, acc[c4 * 4 + 3]);
    }
  }

  const int zz = vox / (DOUT * DOUT), yy = (vox / DOUT) % DOUT, xx = vox % DOUT;
  float* __restrict__ op = out + (size_t)b * 20 * OSLAB + (zz * DOUT + yy) * ORS + xx;
  const float g0 = 1.f / (1.f + expf(-acc[20]));
  const float g1 = 1.f / (1.f + expf(-acc[21]));
  const float g2 = 1.f / (1.f + expf(-acc[22]));
#pragma unroll
  for (int c = 0; c < 5; ++c) op[(size_t)c * OSLAB] = fmaxf(acc[c], 0.f);
#pragma unroll
  for (int c = 0; c < 3; ++c) op[(size_t)(5 + c) * OSLAB] = acc[5 + c] * g0;
#pragma unroll
  for (int c = 0; c < 5; ++c) op[(size_t)(8 + c) * OSLAB] = acc[8 + c] * g1;
#pragma unroll
  for (int c = 0; c < 7; ++c) op[(size_t)(13 + c) * OSLAB] = acc[13 + c] * g2;
}

// conv2 channel-mix (commuted past AvgSpacial) + fc1(relu) + fc2, one block.
__global__ __launch_bounds__(256)
void fc_kernel(const float* __restrict__ S, const float* __restrict__ W2,
               const float* __restrict__ fc1w, const float* __restrict__ fc1b,
               const float* __restrict__ fc2w, const float* __restrict__ fc2b,
               float* __restrict__ out) {
  const int t = threadIdx.x;
  __shared__ float SB[960];
  __shared__ float xs[320];
  __shared__ float hh[800];
  for (int i = t; i < 960; i += 256)
    SB[i] = S[(size_t)i * 2] + S[(size_t)i * 2 + 1];
  __syncthreads();
  for (int i = t; i < 320; i += 256) {
    const int b = i / 20, oc = i % 20;
    float s = 0.f;
    for (int k = 0; k < 60; ++k) s += W2[oc * 60 + k] * SB[b * 60 + k];
    xs[i] = s * (1.0f / 1000.0f);
  }
  __syncthreads();
  for (int i = t; i < 800; i += 256) {
    const int b = i / 50, j = i % 50;
    float s = fc1b[j];
    for (int c = 0; c < 20; ++c) s += xs[b * 20 + c] * fc1w[j * 20 + c];
    hh[i] = fmaxf(s, 0.f);
  }
  __syncthreads();
  for (int i = t; i < 32; i += 256) {
    const int b = i / 2, k = i % 2;
    float s = fc2b[k];
    for (int j = 0; j < 50; ++j) s += hh[b * 50 + j] * fc2w[k * 50 + j];
    out[b * 2 + k] = s;
  }
}

extern "C" void kernel_launch(void* const* d_in, const int* in_sizes, int n_in,
                              void* d_out, int out_size, void* d_ws, size_t ws_size,
                              hipStream_t stream) {
  (void)in_sizes; (void)n_in; (void)out_size;
  const float* inp  = (const float*)d_in[0];
  const float* W0   = (const float*)d_in[1];
  const float* W1   = (const float*)d_in[2];
  const float* W2   = (const float*)d_in[3];
  const float* fc1w = (const float*)d_in[4];
  const float* fc1b = (const float*)d_in[5];
  const float* fc2w = (const float*)d_in[6];
  const float* fc2b = (const float*)d_in[7];
  float* out = (float*)d_out;

  float* ws = (float*)d_ws;
  float* A0 = ws;                      // 12,545,280
  float* A1 = A0 + (size_t)12545280;   // 2,073,600
  float* S  = A1 + (size_t)2073600;    // 2048 (uses 1920)
  float* Z1 = S + 2048;                // variable

  const size_t favail = ws_size / 4;
  const size_t base = (size_t)12545280 + 2073600 + 2048;  // 14,620,928

  // conv0 fused: inp -> A0 (gated, padded 36). grid 8*73*2 = 1168.
  hipLaunchKernelGGL(conv0_kernel, dim3(1168), dim3(256), 0, stream, inp, W0, A0);

  if (favail >= base + (size_t)16 * 60 * 5832) {
    // conv1 A: A0 -> Z1[16][60][5832]. grid 8*12*20*2 = 3840.
    hipLaunchKernelGGL((convA_kernel<20, 33, 18, 36, 0, 16>), dim3(3840), dim3(256), 0, stream,
                       A0, Z1, 0);
    // conv1 B: Z1 -> A1 (gated, padded 20). 16*5832/128 -> 729 blocks.
    hipLaunchKernelGGL((convB_kernel<60, 18, 20, 16>), dim3(729), dim3(128), 0, stream,
                       Z1, W1, A1);
  } else if (favail >= base + (size_t)8 * 60 * 5832) {
    for (int h = 0; h < 2; ++h) {
      hipLaunchKernelGGL((convA_kernel<20, 33, 18, 36, 0, 8>), dim3(1920), dim3(256), 0, stream,
                         A0, Z1, 8 * h);
      hipLaunchKernelGGL((convB_kernel<60, 18, 20, 8>), dim3(365), dim3(128), 0, stream,
                         Z1, W1, A1 + (size_t)8 * h * 20 * 6480);
    }
  } else {
    for (int h = 0; h < 4; ++h) {
      hipLaunchKernelGGL((convA_kernel<20, 33, 18, 36, 0, 4>), dim3(1920), dim3(256), 0, stream,
                         A0, Z1, 4 * h);
      hipLaunchKernelGGL((convB_kernel<60, 18, 20, 4>), dim3(183), dim3(128), 0, stream,
                         Z1, W1, A1 + (size_t)4 * h * 20 * 6480);
    }
  }

  // conv2 phase A + spatial reduce: A1 -> S[16][60][2]. grid 8*2*20*2 = 640.
  hipLaunchKernelGGL((convA_kernel<20, 18, 10, 20, 1, 16>), dim3(640), dim3(256), 0, stream,
                     A1, S, 0);
  // conv2 mix (commuted) + fc.
  hipLaunchKernelGGL(fc_kernel, dim3(1), dim3(256), 0, stream, S, W2, fc1w, fc1b, fc2w, fc2b,
                     out);
}